// Round 2
// baseline (2228.707 us; speedup 1.0000x reference)
//
#include <hip/hip_runtime.h>
#include <math.h>

#define Bz 4
#define Tz 4096
#define Dz 1024
#define Hz 16
#define HDz 64
#define BHz 64
#define Mz 16384

// ---------------- trig table: tbl[t][j][{cos,sin}] , t<4096, j<64 ----------------
__global__ __launch_bounds__(256) void k_trig(float* __restrict__ tbl) {
    int t = blockIdx.x * 256 + threadIdx.x;   // grid 16 -> t in [0,4096)
    float ft = (float)t;
    for (int j = 0; j < 64; ++j) {
        int kidx = (j < 32) ? j : (j - 32);
        double e = (double)(2 * kidx) / 64.0;         // exact, same value as np float32
        float p = (float)pow(10000.0, e);             // correctly-rounded f32 of 10000^e
        float invf = 1.0f / p;                        // mirror np: pow then divide
        float arg = ft * invf;                        // single f32 multiply, matches np einsum
        tbl[t * 128 + j * 2 + 0] = cosf(arg);
        tbl[t * 128 + j * 2 + 1] = sinf(arg);
    }
}

// ---------------- QKV GEMM: C[16384,3072] = x @ W_attn + b ; epilogue RoPE + head layout ----
__global__ __launch_bounds__(256) void k_qkv(const float* __restrict__ A,
                                             const float* __restrict__ W,
                                             const float* __restrict__ bias,
                                             const float* __restrict__ tbl,
                                             float* __restrict__ Qb,
                                             float* __restrict__ Kb,
                                             float* __restrict__ Vb)
{
    __shared__ float As[16][128];
    __shared__ float Bs[16][128];
    const int tid = threadIdx.x;
    const int n0 = blockIdx.x * 128;
    const int m0 = blockIdx.y * 128;
    const int tx = tid & 15, ty = tid >> 4;
    float acc[8][8];
#pragma unroll
    for (int i = 0; i < 8; ++i)
#pragma unroll
        for (int j = 0; j < 8; ++j) acc[i][j] = 0.f;

    for (int kt = 0; kt < 1024; kt += 16) {
#pragma unroll
        for (int i = 0; i < 2; ++i) {
            int idx = tid * 2 + i;
            int row = idx >> 2;
            int kq = idx & 3;
            float4 a4 = *(const float4*)(A + (size_t)(m0 + row) * 1024 + kt + kq * 4);
            As[kq * 4 + 0][row] = a4.x;
            As[kq * 4 + 1][row] = a4.y;
            As[kq * 4 + 2][row] = a4.z;
            As[kq * 4 + 3][row] = a4.w;
        }
#pragma unroll
        for (int i = 0; i < 2; ++i) {
            int idx = tid * 2 + i;
            int rr = idx >> 5;
            int c4 = idx & 31;
            *(float4*)(&Bs[rr][c4 * 4]) = *(const float4*)(W + (size_t)(kt + rr) * 3072 + n0 + c4 * 4);
        }
        __syncthreads();
#pragma unroll
        for (int kk = 0; kk < 16; ++kk) {
            float a[8], b[8];
            *(float4*)(a)     = *(const float4*)(&As[kk][ty * 8]);
            *(float4*)(a + 4) = *(const float4*)(&As[kk][ty * 8 + 4]);
            *(float4*)(b)     = *(const float4*)(&Bs[kk][tx * 8]);
            *(float4*)(b + 4) = *(const float4*)(&Bs[kk][tx * 8 + 4]);
#pragma unroll
            for (int i = 0; i < 8; ++i)
#pragma unroll
                for (int j = 0; j < 8; ++j)
                    acc[i][j] = fmaf(a[i], b[j], acc[i][j]);
        }
        __syncthreads();
    }
    // epilogue
    const int cbase = n0 + tx * 8;       // 8 contiguous cols, never straddle a head (64) boundary
    const int part = cbase >> 10;        // 0=q 1=k 2=v
    const int cc = cbase & 1023;
    const int h = cc >> 6;
    const int dbase = cc & 63;
    const int bb = m0 >> 12;
    const int tbase = (m0 & 4095) + ty * 8;
    float bv[8];
#pragma unroll
    for (int j = 0; j < 8; ++j) bv[j] = bias[cbase + j];

    if (part == 2) {
#pragma unroll
        for (int i = 0; i < 8; ++i) {
            int t = tbase + i;
            float* dst = Vb + ((size_t)(bb * 16 + h) * 4096 + t) * 64 + dbase;
            *(float4*)(dst)     = make_float4(acc[i][0] + bv[0], acc[i][1] + bv[1], acc[i][2] + bv[2], acc[i][3] + bv[3]);
            *(float4*)(dst + 4) = make_float4(acc[i][4] + bv[4], acc[i][5] + bv[5], acc[i][6] + bv[6], acc[i][7] + bv[7]);
        }
    } else {
        float* DST = (part == 0) ? Qb : Kb;
#pragma unroll
        for (int i = 0; i < 8; ++i) {
            int t = tbase + i;
            const float4* tb = (const float4*)(tbl + t * 128 + dbase * 2);
            float o[8];
#pragma unroll
            for (int jp = 0; jp < 4; ++jp) {
                float4 cs = tb[jp];  // cos(j_even), sin(j_even), cos(j_odd), sin(j_odd)
                float ae = acc[i][jp * 2]     + bv[jp * 2];
                float ao = acc[i][jp * 2 + 1] + bv[jp * 2 + 1];
                o[jp * 2]     = ae * cs.x - ao * cs.y;   // even: x*cos - x_odd*sin
                o[jp * 2 + 1] = ao * cs.z + ae * cs.w;   // odd : x*cos + x_even*sin
            }
            float* dst = DST + ((size_t)(bb * 16 + h) * 4096 + t) * 64 + dbase;
            *(float4*)(dst)     = make_float4(o[0], o[1], o[2], o[3]);
            *(float4*)(dst + 4) = make_float4(o[4], o[5], o[6], o[7]);
        }
    }
}

// ---------------- bucket argmax: b_idx[bh][t] over [q.R , -q.R] (hash 0 only) --------------
__global__ __launch_bounds__(64) void k_bucket(const float* __restrict__ Q,
                                               const float* __restrict__ R,
                                               int* __restrict__ bidx)
{
    __shared__ float Qs[64][65];
    __shared__ float Rs[64][32];
    const int tid = threadIdx.x;
    const int g0 = blockIdx.x * 64;     // 64 tokens per block, never straddles a bh row
    const int bh = g0 >> 12;
    const int t0 = g0 & 4095;
#pragma unroll
    for (int m = 0; m < 32; ++m) Rs[tid][m] = R[tid * 64 + m];   // R[d][hash=0][m], stride 64
    const float* qbase = Q + ((size_t)bh * Tz + t0) * 64;
    for (int r = 0; r < 64; ++r) Qs[r][tid] = qbase[(size_t)r * 64 + tid];
    __syncthreads();

    float s[32];
#pragma unroll
    for (int m = 0; m < 32; ++m) s[m] = 0.f;
    for (int d = 0; d < 64; ++d) {
        float qd = Qs[tid][d];
#pragma unroll
        for (int m4 = 0; m4 < 8; ++m4) {
            float4 r4 = *(const float4*)(&Rs[d][m4 * 4]);
            s[m4 * 4 + 0] = fmaf(qd, r4.x, s[m4 * 4 + 0]);
            s[m4 * 4 + 1] = fmaf(qd, r4.y, s[m4 * 4 + 1]);
            s[m4 * 4 + 2] = fmaf(qd, r4.z, s[m4 * 4 + 2]);
            s[m4 * 4 + 3] = fmaf(qd, r4.w, s[m4 * 4 + 3]);
        }
    }
    float best = s[0];
    int bi = 0;
#pragma unroll
    for (int m = 1; m < 64; ++m) {
        float v = (m < 32) ? s[m] : -s[m - 32];
        if (v > best) { best = v; bi = m; }          // strict > == np.argmax first-max
    }
    bidx[g0 + tid] = bi;
}

// ---------------- stable counting sort per bh row (matches stable argsort) -----------------
__global__ __launch_bounds__(64) void k_sort(const int* __restrict__ bidx,
                                             int* __restrict__ sidx)
{
    __shared__ int lb[4096];
    __shared__ int ls[4096];
    const int tid = threadIdx.x;
    const int bh = blockIdx.x;
    const int* brow = bidx + (size_t)bh * 4096;
    for (int i = tid; i < 4096; i += 64) lb[i] = brow[i];
    __syncthreads();
    int cnt = 0;
    for (int i = 0; i < 4096; ++i) cnt += (lb[i] == tid);
    int run = cnt;
#pragma unroll
    for (int off = 1; off < 64; off <<= 1) {
        int n = __shfl_up(run, off, 64);
        if (tid >= off) run += n;
    }
    int pos = run - cnt;                 // exclusive prefix = start of bucket tid
    for (int i = 0; i < 4096; ++i) {
        if (lb[i] == tid) { ls[pos] = i; ++pos; }
    }
    __syncthreads();
    int* srow = sidx + (size_t)bh * 4096;
    for (int i = tid; i < 4096; i += 64) srow[i] = ls[i];
}

// ---------------- chunked attention over sorted order; scatter-unsort into AO --------------
__global__ __launch_bounds__(256) void k_attn(const float* __restrict__ Q,
                                              const float* __restrict__ Kb,
                                              const float* __restrict__ Vb,
                                              const int* __restrict__ sidx,
                                              float* __restrict__ AO)
{
    __shared__ float smem[16384];        // 64 KB: Qt[64][128]@0, Kt[64][128]@8192 ; Pt[128][128] overlays @0
    float* Qt = smem;
    float* Kt = smem + 8192;
    float* Pt = smem;
    const int bh = blockIdx.y;
    const int ch = blockIdx.x;
    const int tid = threadIdx.x;
    const int* srow = sidx + (size_t)bh * Tz + ch * 128;

    // gather Q,K (sorted rows) transposed into LDS
    {
        int r = tid >> 1;
        int ds = (tid & 1) * 32;
        int orig = srow[r];
        const float* qp = Q  + ((size_t)bh * Tz + orig) * 64 + ds;
        const float* kp = Kb + ((size_t)bh * Tz + orig) * 64 + ds;
#pragma unroll
        for (int j4 = 0; j4 < 8; ++j4) {
            float4 q4 = *(const float4*)(qp + j4 * 4);
            float4 k4 = *(const float4*)(kp + j4 * 4);
            int d = ds + j4 * 4;
            Qt[(d + 0) * 128 + r] = q4.x; Qt[(d + 1) * 128 + r] = q4.y;
            Qt[(d + 2) * 128 + r] = q4.z; Qt[(d + 3) * 128 + r] = q4.w;
            Kt[(d + 0) * 128 + r] = k4.x; Kt[(d + 1) * 128 + r] = k4.y;
            Kt[(d + 2) * 128 + r] = k4.z; Kt[(d + 3) * 128 + r] = k4.w;
        }
    }
    __syncthreads();

    const int tx = tid & 15, ty = tid >> 4;   // 16x16 threads, 8x8 tile each
    float acc[8][8];
#pragma unroll
    for (int i = 0; i < 8; ++i)
#pragma unroll
        for (int j = 0; j < 8; ++j) acc[i][j] = 0.f;

#pragma unroll 2
    for (int d = 0; d < 64; ++d) {
        float a[8], b[8];
        *(float4*)(a)     = *(const float4*)(Qt + d * 128 + ty * 8);
        *(float4*)(a + 4) = *(const float4*)(Qt + d * 128 + ty * 8 + 4);
        *(float4*)(b)     = *(const float4*)(Kt + d * 128 + tx * 8);
        *(float4*)(b + 4) = *(const float4*)(Kt + d * 128 + tx * 8 + 4);
#pragma unroll
        for (int i = 0; i < 8; ++i)
#pragma unroll
            for (int j = 0; j < 8; ++j)
                acc[i][j] = fmaf(a[i], b[j], acc[i][j]);
    }

    // row softmax (rows = ty*8+i, cols spread across the 16 tx lanes -> shuffle reduce)
    float rsum[8];
#pragma unroll
    for (int i = 0; i < 8; ++i) {
        float m = -1e30f;
#pragma unroll
        for (int j = 0; j < 8; ++j) { acc[i][j] *= 0.125f; m = fmaxf(m, acc[i][j]); }
#pragma unroll
        for (int off = 1; off < 16; off <<= 1) m = fmaxf(m, __shfl_xor(m, off, 16));
        float s = 0.f;
#pragma unroll
        for (int j = 0; j < 8; ++j) { float p = expf(acc[i][j] - m); acc[i][j] = p; s += p; }
#pragma unroll
        for (int off = 1; off < 16; off <<= 1) s += __shfl_xor(s, off, 16);
        rsum[i] = s;
    }
    __syncthreads();   // all Qt/Kt reads done; safe to overlay Pt

    // write P transposed: Pt[c][r], r swizzled by (tx&3)<<3 to spread banks
#pragma unroll
    for (int j = 0; j < 8; ++j) {
        int c = tx * 8 + j;
        int rb = c * 128 + ((ty * 8) ^ ((tx & 3) << 3));
        *(float4*)(Pt + rb)     = make_float4(acc[0][j], acc[1][j], acc[2][j], acc[3][j]);
        *(float4*)(Pt + rb + 4) = make_float4(acc[4][j], acc[5][j], acc[6][j], acc[7][j]);
    }
    __syncthreads();

    // O = P @ V ; V streamed from global (L1-resident 32KB/block), rows via uniform idx loads
    float oacc[8][4];
#pragma unroll
    for (int i = 0; i < 8; ++i)
#pragma unroll
        for (int j = 0; j < 4; ++j) oacc[i][j] = 0.f;

    const int tr = ty;   // rows tr*8..+8
    const int tc = tx;   // cols tc*4..+4
#pragma unroll 4
    for (int k = 0; k < 128; ++k) {
        int orig = srow[k];
        float4 b4 = *(const float4*)(Vb + ((size_t)bh * Tz + orig) * 64 + tc * 4);
        int rb = k * 128 + ((tr * 8) ^ (((k >> 3) & 3) << 3));
        float a[8];
        *(float4*)(a)     = *(const float4*)(Pt + rb);
        *(float4*)(a + 4) = *(const float4*)(Pt + rb + 4);
#pragma unroll
        for (int i = 0; i < 8; ++i) {
            oacc[i][0] = fmaf(a[i], b4.x, oacc[i][0]);
            oacc[i][1] = fmaf(a[i], b4.y, oacc[i][1]);
            oacc[i][2] = fmaf(a[i], b4.z, oacc[i][2]);
            oacc[i][3] = fmaf(a[i], b4.w, oacc[i][3]);
        }
    }

    const int bb = bh >> 4;
    const int hh = bh & 15;
#pragma unroll
    for (int i = 0; i < 8; ++i) {
        int r = tr * 8 + i;
        int orig = srow[r];
        float inv = 1.0f / rsum[i];
        *(float4*)(AO + ((size_t)bb * 4096 + orig) * 1024 + hh * 64 + tc * 4) =
            make_float4(oacc[i][0] * inv, oacc[i][1] * inv, oacc[i][2] * inv, oacc[i][3] * inv);
    }
}

// ---------------- output projection: d_out = AO @ W_proj + b_proj -------------------------
__global__ __launch_bounds__(256) void k_proj(const float* __restrict__ A,
                                              const float* __restrict__ W,
                                              const float* __restrict__ bias,
                                              float* __restrict__ Cout)
{
    __shared__ float As[16][128];
    __shared__ float Bs[16][128];
    const int tid = threadIdx.x;
    const int n0 = blockIdx.x * 128;
    const int m0 = blockIdx.y * 128;
    const int tx = tid & 15, ty = tid >> 4;
    float acc[8][8];
#pragma unroll
    for (int i = 0; i < 8; ++i)
#pragma unroll
        for (int j = 0; j < 8; ++j) acc[i][j] = 0.f;

    for (int kt = 0; kt < 1024; kt += 16) {
#pragma unroll
        for (int i = 0; i < 2; ++i) {
            int idx = tid * 2 + i;
            int row = idx >> 2;
            int kq = idx & 3;
            float4 a4 = *(const float4*)(A + (size_t)(m0 + row) * 1024 + kt + kq * 4);
            As[kq * 4 + 0][row] = a4.x;
            As[kq * 4 + 1][row] = a4.y;
            As[kq * 4 + 2][row] = a4.z;
            As[kq * 4 + 3][row] = a4.w;
        }
#pragma unroll
        for (int i = 0; i < 2; ++i) {
            int idx = tid * 2 + i;
            int rr = idx >> 5;
            int c4 = idx & 31;
            *(float4*)(&Bs[rr][c4 * 4]) = *(const float4*)(W + (size_t)(kt + rr) * 1024 + n0 + c4 * 4);
        }
        __syncthreads();
#pragma unroll
        for (int kk = 0; kk < 16; ++kk) {
            float a[8], b[8];
            *(float4*)(a)     = *(const float4*)(&As[kk][ty * 8]);
            *(float4*)(a + 4) = *(const float4*)(&As[kk][ty * 8 + 4]);
            *(float4*)(b)     = *(const float4*)(&Bs[kk][tx * 8]);
            *(float4*)(b + 4) = *(const float4*)(&Bs[kk][tx * 8 + 4]);
#pragma unroll
            for (int i = 0; i < 8; ++i)
#pragma unroll
                for (int j = 0; j < 8; ++j)
                    acc[i][j] = fmaf(a[i], b[j], acc[i][j]);
        }
        __syncthreads();
    }
    float bv[8];
#pragma unroll
    for (int j = 0; j < 8; ++j) bv[j] = bias[n0 + tx * 8 + j];
#pragma unroll
    for (int i = 0; i < 8; ++i) {
        int r = m0 + ty * 8 + i;
        float* dst = Cout + (size_t)r * 1024 + n0 + tx * 8;
        *(float4*)(dst)     = make_float4(acc[i][0] + bv[0], acc[i][1] + bv[1], acc[i][2] + bv[2], acc[i][3] + bv[3]);
        *(float4*)(dst + 4) = make_float4(acc[i][4] + bv[4], acc[i][5] + bv[5], acc[i][6] + bv[6], acc[i][7] + bv[7]);
    }
}

extern "C" void kernel_launch(void* const* d_in, const int* in_sizes, int n_in,
                              void* d_out, int out_size, void* d_ws, size_t ws_size,
                              hipStream_t stream)
{
    const float* x      = (const float*)d_in[0];
    const float* W_attn = (const float*)d_in[1];
    const float* b_attn = (const float*)d_in[2];
    const float* W_proj = (const float*)d_in[3];
    const float* b_proj = (const float*)d_in[4];
    const float* R      = (const float*)d_in[5];
    float* out = (float*)d_out;

    // Workspace layout (196 MB total). V aliases d_out (64 MB, exactly BHz*Tz*64 floats):
    // k_qkv writes V -> k_attn reads V -> k_proj overwrites d_out last. Stream-ordered, safe.
    char* ws = (char*)d_ws;
    const size_t SZ_TBL = (size_t)4096 * 128 * 4;         // 2 MB
    const size_t SZ_HED = (size_t)BHz * Tz * 64 * 4;      // 64 MB each
    float* tbl = (float*)(ws);
    float* Qb  = (float*)(ws + SZ_TBL);
    float* Kb  = (float*)(ws + SZ_TBL + SZ_HED);
    float* AO  = (float*)(ws + SZ_TBL + 2 * SZ_HED);
    int*  bidx = (int*)  (ws + SZ_TBL + 3 * SZ_HED);
    int*  sidx = bidx + (size_t)BHz * Tz;
    float* Vb  = (float*)d_out;                           // scratch until k_proj runs

    k_trig  <<<dim3(16),      dim3(256), 0, stream>>>(tbl);
    k_qkv   <<<dim3(24, 128), dim3(256), 0, stream>>>(x, W_attn, b_attn, tbl, Qb, Kb, Vb);
    k_bucket<<<dim3(4096),    dim3(64),  0, stream>>>(Qb, R, bidx);
    k_sort  <<<dim3(64),      dim3(64),  0, stream>>>(bidx, sidx);
    k_attn  <<<dim3(32, 64),  dim3(256), 0, stream>>>(Qb, Kb, Vb, sidx, AO);
    k_proj  <<<dim3(8, 128),  dim3(256), 0, stream>>>(AO, W_proj, b_proj, out);
}

// Round 3
// 1753.922 us; speedup vs baseline: 1.2707x; 1.2707x over previous
//
#include <hip/hip_runtime.h>
#include <math.h>

#define Bz 4
#define Tz 4096
#define Dz 1024
#define Hz 16
#define HDz 64
#define BHz 64
#define Mz 16384

typedef __attribute__((ext_vector_type(8))) short short8;
typedef __attribute__((ext_vector_type(8))) __bf16 bf16x8;
typedef __attribute__((ext_vector_type(4))) float floatx4;

__device__ inline unsigned short f2bf(float f) {
    unsigned u = __float_as_uint(f);
    u = (u + 0x7fffu + ((u >> 16) & 1u)) >> 16;   // RNE; finite data only
    return (unsigned short)u;
}
__device__ inline float bf2f(unsigned short h) {
    return __uint_as_float(((unsigned)h) << 16);
}

// ---------------- trig table: tbl[t][j][{cos,sin}] , t<4096, j<64 ----------------
__global__ __launch_bounds__(256) void k_trig(float* __restrict__ tbl) {
    int t = blockIdx.x * 256 + threadIdx.x;   // grid 16 -> t in [0,4096)
    float ft = (float)t;
    for (int j = 0; j < 64; ++j) {
        int kidx = (j < 32) ? j : (j - 32);
        double e = (double)(2 * kidx) / 64.0;
        float p = (float)pow(10000.0, e);
        float invf = 1.0f / p;
        float arg = ft * invf;
        tbl[t * 128 + j * 2 + 0] = cosf(arg);
        tbl[t * 128 + j * 2 + 1] = sinf(arg);
    }
}

// ---------------- split fp32 x -> bf16 hi/lo ----------------
__global__ __launch_bounds__(256) void k_cvtA(const float* __restrict__ x,
                                              unsigned short* __restrict__ xh,
                                              unsigned short* __restrict__ xl)
{
    size_t i4 = (size_t)blockIdx.x * 256 + threadIdx.x;   // 4 floats per thread
    float4 v = *(const float4*)(x + i4 * 4);
    ushort4 h, l;
    h.x = f2bf(v.x); l.x = f2bf(v.x - bf2f(h.x));
    h.y = f2bf(v.y); l.y = f2bf(v.y - bf2f(h.y));
    h.z = f2bf(v.z); l.z = f2bf(v.z - bf2f(h.z));
    h.w = f2bf(v.w); l.w = f2bf(v.w - bf2f(h.w));
    *(ushort4*)(xh + i4 * 4) = h;
    *(ushort4*)(xl + i4 * 4) = l;
}

// ---------------- transpose+split W_attn K/V cols: Wt[n][k] = W[k][1024+n] ----------------
__global__ __launch_bounds__(256) void k_cvtB(const float* __restrict__ W,
                                              unsigned short* __restrict__ wh,
                                              unsigned short* __restrict__ wl)
{
    __shared__ float tile[64][65];
    const int n0 = blockIdx.x * 64;   // 32 blocks
    const int k0 = blockIdx.y * 64;   // 16 blocks
    const int tid = threadIdx.x;
#pragma unroll
    for (int i = 0; i < 16; ++i) {
        int flat = i * 256 + tid;
        int kr = flat >> 6, nc = flat & 63;
        tile[kr][nc] = W[(size_t)(k0 + kr) * 3072 + 1024 + n0 + nc];
    }
    __syncthreads();
#pragma unroll
    for (int i = 0; i < 16; ++i) {
        int flat = i * 256 + tid;
        int nr = flat >> 6, kc = flat & 63;
        float v = tile[kc][nr];
        unsigned short h = f2bf(v);
        wh[(size_t)(n0 + nr) * 1024 + k0 + kc] = h;
        wl[(size_t)(n0 + nr) * 1024 + k0 + kc] = f2bf(v - bf2f(h));
    }
}

// ---------------- Q-only fp32 GEMM (bit-identical to round-2 k_qkv, grid x=8) -------------
__global__ __launch_bounds__(256) void k_qkv(const float* __restrict__ A,
                                             const float* __restrict__ W,
                                             const float* __restrict__ bias,
                                             const float* __restrict__ tbl,
                                             float* __restrict__ Qb,
                                             float* __restrict__ Kb,
                                             float* __restrict__ Vb)
{
    __shared__ float As[16][128];
    __shared__ float Bs[16][128];
    const int tid = threadIdx.x;
    const int n0 = blockIdx.x * 128;
    const int m0 = blockIdx.y * 128;
    const int tx = tid & 15, ty = tid >> 4;
    float acc[8][8];
#pragma unroll
    for (int i = 0; i < 8; ++i)
#pragma unroll
        for (int j = 0; j < 8; ++j) acc[i][j] = 0.f;

    for (int kt = 0; kt < 1024; kt += 16) {
#pragma unroll
        for (int i = 0; i < 2; ++i) {
            int idx = tid * 2 + i;
            int row = idx >> 2;
            int kq = idx & 3;
            float4 a4 = *(const float4*)(A + (size_t)(m0 + row) * 1024 + kt + kq * 4);
            As[kq * 4 + 0][row] = a4.x;
            As[kq * 4 + 1][row] = a4.y;
            As[kq * 4 + 2][row] = a4.z;
            As[kq * 4 + 3][row] = a4.w;
        }
#pragma unroll
        for (int i = 0; i < 2; ++i) {
            int idx = tid * 2 + i;
            int rr = idx >> 5;
            int c4 = idx & 31;
            *(float4*)(&Bs[rr][c4 * 4]) = *(const float4*)(W + (size_t)(kt + rr) * 3072 + n0 + c4 * 4);
        }
        __syncthreads();
#pragma unroll
        for (int kk = 0; kk < 16; ++kk) {
            float a[8], b[8];
            *(float4*)(a)     = *(const float4*)(&As[kk][ty * 8]);
            *(float4*)(a + 4) = *(const float4*)(&As[kk][ty * 8 + 4]);
            *(float4*)(b)     = *(const float4*)(&Bs[kk][tx * 8]);
            *(float4*)(b + 4) = *(const float4*)(&Bs[kk][tx * 8 + 4]);
#pragma unroll
            for (int i = 0; i < 8; ++i)
#pragma unroll
                for (int j = 0; j < 8; ++j)
                    acc[i][j] = fmaf(a[i], b[j], acc[i][j]);
        }
        __syncthreads();
    }
    const int cbase = n0 + tx * 8;
    const int part = cbase >> 10;        // always 0 (Q) with grid x=8
    const int cc = cbase & 1023;
    const int h = cc >> 6;
    const int dbase = cc & 63;
    const int bb = m0 >> 12;
    const int tbase = (m0 & 4095) + ty * 8;
    float bv[8];
#pragma unroll
    for (int j = 0; j < 8; ++j) bv[j] = bias[cbase + j];

    if (part == 2) {
#pragma unroll
        for (int i = 0; i < 8; ++i) {
            int t = tbase + i;
            float* dst = Vb + ((size_t)(bb * 16 + h) * 4096 + t) * 64 + dbase;
            *(float4*)(dst)     = make_float4(acc[i][0] + bv[0], acc[i][1] + bv[1], acc[i][2] + bv[2], acc[i][3] + bv[3]);
            *(float4*)(dst + 4) = make_float4(acc[i][4] + bv[4], acc[i][5] + bv[5], acc[i][6] + bv[6], acc[i][7] + bv[7]);
        }
    } else {
        float* DST = (part == 0) ? Qb : Kb;
#pragma unroll
        for (int i = 0; i < 8; ++i) {
            int t = tbase + i;
            const float4* tb = (const float4*)(tbl + t * 128 + dbase * 2);
            float o[8];
#pragma unroll
            for (int jp = 0; jp < 4; ++jp) {
                float4 cs = tb[jp];
                float ae = acc[i][jp * 2]     + bv[jp * 2];
                float ao = acc[i][jp * 2 + 1] + bv[jp * 2 + 1];
                o[jp * 2]     = ae * cs.x - ao * cs.y;
                o[jp * 2 + 1] = ao * cs.z + ae * cs.w;
            }
            float* dst = DST + ((size_t)(bb * 16 + h) * 4096 + t) * 64 + dbase;
            *(float4*)(dst)     = make_float4(o[0], o[1], o[2], o[3]);
            *(float4*)(dst + 4) = make_float4(o[4], o[5], o[6], o[7]);
        }
    }
}

// ---------------- K,V via split-bf16 MFMA: C = xh*Wh + xh*Wl + xl*Wh  ----------------
// 128x128 tile, BK=32, 4 waves of 64x64, mfma_f32_16x16x32_bf16.
__global__ __launch_bounds__(256) void k_kv(const unsigned short* __restrict__ xh,
                                            const unsigned short* __restrict__ xl,
                                            const unsigned short* __restrict__ wh,
                                            const unsigned short* __restrict__ wl,
                                            const float* __restrict__ bias,
                                            const float* __restrict__ tbl,
                                            float* __restrict__ Kb,
                                            float* __restrict__ Vb)
{
    __shared__ unsigned short Ah[128 * 32], Al[128 * 32], Bh[128 * 32], Bl[128 * 32];
    const int tid = threadIdx.x;
    const int lane = tid & 63, wv = tid >> 6;
    const int n0 = blockIdx.x * 128;   // 16 blocks; n<1024 -> K (rope), else V
    const int m0 = blockIdx.y * 128;   // 128 blocks
    const int wm = (wv & 1) * 64, wn = (wv >> 1) * 64;
    const int sr = tid >> 2, sc = tid & 3;    // staging: row sr (+64), 8-elem chunk sc
    const int fr = lane & 15, fq = lane >> 4; // fragment row / k-quad

    floatx4 acc[4][4];
#pragma unroll
    for (int i = 0; i < 4; ++i)
#pragma unroll
        for (int j = 0; j < 4; ++j) acc[i][j] = (floatx4){0.f, 0.f, 0.f, 0.f};

    for (int kt = 0; kt < 1024; kt += 32) {
        __syncthreads();
#pragma unroll
        for (int s = 0; s < 2; ++s) {
            int row = s * 64 + sr;
            size_t ga = (size_t)(m0 + row) * 1024 + kt + sc * 8;
            size_t gb = (size_t)(n0 + row) * 1024 + kt + sc * 8;
            *(short8*)(&Ah[row * 32 + sc * 8]) = *(const short8*)(xh + ga);
            *(short8*)(&Al[row * 32 + sc * 8]) = *(const short8*)(xl + ga);
            *(short8*)(&Bh[row * 32 + sc * 8]) = *(const short8*)(wh + gb);
            *(short8*)(&Bl[row * 32 + sc * 8]) = *(const short8*)(wl + gb);
        }
        __syncthreads();

        bf16x8 afh[4], afl[4], bfh[4], bfl[4];
#pragma unroll
        for (int i = 0; i < 4; ++i) {
            afh[i] = __builtin_bit_cast(bf16x8, *(const short8*)(&Ah[(wm + i * 16 + fr) * 32 + fq * 8]));
            afl[i] = __builtin_bit_cast(bf16x8, *(const short8*)(&Al[(wm + i * 16 + fr) * 32 + fq * 8]));
            bfh[i] = __builtin_bit_cast(bf16x8, *(const short8*)(&Bh[(wn + i * 16 + fr) * 32 + fq * 8]));
            bfl[i] = __builtin_bit_cast(bf16x8, *(const short8*)(&Bl[(wn + i * 16 + fr) * 32 + fq * 8]));
        }
#pragma unroll
        for (int i = 0; i < 4; ++i)
#pragma unroll
            for (int j = 0; j < 4; ++j) {
                acc[i][j] = __builtin_amdgcn_mfma_f32_16x16x32_bf16(afh[i], bfh[j], acc[i][j], 0, 0, 0);
                acc[i][j] = __builtin_amdgcn_mfma_f32_16x16x32_bf16(afh[i], bfl[j], acc[i][j], 0, 0, 0);
                acc[i][j] = __builtin_amdgcn_mfma_f32_16x16x32_bf16(afl[i], bfh[j], acc[i][j], 0, 0, 0);
            }
    }

    // epilogue: C/D layout col=lane&15, row=fq*4+reg. nn in [0,2048): col 1024+nn of W_attn.
#pragma unroll
    for (int j = 0; j < 4; ++j) {
        int nn = n0 + wn + j * 16 + fr;
        float bv = bias[1024 + nn];
#pragma unroll
        for (int i = 0; i < 4; ++i) {
#pragma unroll
            for (int r = 0; r < 4; ++r) {
                int mm = m0 + wm + i * 16 + fq * 4 + r;
                int t = mm & 4095, bb = mm >> 12;
                float y = acc[i][j][r] + bv;
                if (nn < 1024) {                     // K: apply rope (uniform per block)
                    int h = nn >> 6, d = nn & 63;
                    float part = __shfl_xor(y, 1);   // partner column (d^1), same (i,j,r)
                    float c = tbl[t * 128 + d * 2];
                    float s = tbl[t * 128 + d * 2 + 1];
                    float o = (d & 1) ? fmaf(part, s, y * c) : fmaf(-part, s, y * c);
                    Kb[((size_t)(bb * 16 + h) * 4096 + t) * 64 + d] = o;
                } else {                             // V
                    int nv = nn - 1024;
                    int h = nv >> 6, d = nv & 63;
                    Vb[((size_t)(bb * 16 + h) * 4096 + t) * 64 + d] = y;
                }
            }
        }
    }
}

// ---------------- bucket argmax ----------------
__global__ __launch_bounds__(64) void k_bucket(const float* __restrict__ Q,
                                               const float* __restrict__ R,
                                               int* __restrict__ bidx)
{
    __shared__ float Qs[64][65];
    __shared__ float Rs[64][32];
    const int tid = threadIdx.x;
    const int g0 = blockIdx.x * 64;
    const int bh = g0 >> 12;
    const int t0 = g0 & 4095;
#pragma unroll
    for (int m = 0; m < 32; ++m) Rs[tid][m] = R[tid * 64 + m];
    const float* qbase = Q + ((size_t)bh * Tz + t0) * 64;
    for (int r = 0; r < 64; ++r) Qs[r][tid] = qbase[(size_t)r * 64 + tid];
    __syncthreads();

    float s[32];
#pragma unroll
    for (int m = 0; m < 32; ++m) s[m] = 0.f;
    for (int d = 0; d < 64; ++d) {
        float qd = Qs[tid][d];
#pragma unroll
        for (int m4 = 0; m4 < 8; ++m4) {
            float4 r4 = *(const float4*)(&Rs[d][m4 * 4]);
            s[m4 * 4 + 0] = fmaf(qd, r4.x, s[m4 * 4 + 0]);
            s[m4 * 4 + 1] = fmaf(qd, r4.y, s[m4 * 4 + 1]);
            s[m4 * 4 + 2] = fmaf(qd, r4.z, s[m4 * 4 + 2]);
            s[m4 * 4 + 3] = fmaf(qd, r4.w, s[m4 * 4 + 3]);
        }
    }
    float best = s[0];
    int bi = 0;
#pragma unroll
    for (int m = 1; m < 64; ++m) {
        float v = (m < 32) ? s[m] : -s[m - 32];
        if (v > best) { best = v; bi = m; }
    }
    bidx[g0 + tid] = bi;
}

// ---------------- stable counting sort ----------------
__global__ __launch_bounds__(64) void k_sort(const int* __restrict__ bidx,
                                             int* __restrict__ sidx)
{
    __shared__ int lb[4096];
    __shared__ int ls[4096];
    const int tid = threadIdx.x;
    const int bh = blockIdx.x;
    const int* brow = bidx + (size_t)bh * 4096;
    for (int i = tid; i < 4096; i += 64) lb[i] = brow[i];
    __syncthreads();
    int cnt = 0;
    for (int i = 0; i < 4096; ++i) cnt += (lb[i] == tid);
    int run = cnt;
#pragma unroll
    for (int off = 1; off < 64; off <<= 1) {
        int n = __shfl_up(run, off, 64);
        if (tid >= off) run += n;
    }
    int pos = run - cnt;
    for (int i = 0; i < 4096; ++i) {
        if (lb[i] == tid) { ls[pos] = i; ++pos; }
    }
    __syncthreads();
    int* srow = sidx + (size_t)bh * 4096;
    for (int i = tid; i < 4096; i += 64) srow[i] = ls[i];
}

// ---------------- chunked attention ----------------
__global__ __launch_bounds__(256) void k_attn(const float* __restrict__ Q,
                                              const float* __restrict__ Kb,
                                              const float* __restrict__ Vb,
                                              const int* __restrict__ sidx,
                                              float* __restrict__ AO)
{
    __shared__ float smem[16384];
    float* Qt = smem;
    float* Kt = smem + 8192;
    float* Pt = smem;
    const int bh = blockIdx.y;
    const int ch = blockIdx.x;
    const int tid = threadIdx.x;
    const int* srow = sidx + (size_t)bh * Tz + ch * 128;

    {
        int r = tid >> 1;
        int ds = (tid & 1) * 32;
        int orig = srow[r];
        const float* qp = Q  + ((size_t)bh * Tz + orig) * 64 + ds;
        const float* kp = Kb + ((size_t)bh * Tz + orig) * 64 + ds;
#pragma unroll
        for (int j4 = 0; j4 < 8; ++j4) {
            float4 q4 = *(const float4*)(qp + j4 * 4);
            float4 k4 = *(const float4*)(kp + j4 * 4);
            int d = ds + j4 * 4;
            Qt[(d + 0) * 128 + r] = q4.x; Qt[(d + 1) * 128 + r] = q4.y;
            Qt[(d + 2) * 128 + r] = q4.z; Qt[(d + 3) * 128 + r] = q4.w;
            Kt[(d + 0) * 128 + r] = k4.x; Kt[(d + 1) * 128 + r] = k4.y;
            Kt[(d + 2) * 128 + r] = k4.z; Kt[(d + 3) * 128 + r] = k4.w;
        }
    }
    __syncthreads();

    const int tx = tid & 15, ty = tid >> 4;
    float acc[8][8];
#pragma unroll
    for (int i = 0; i < 8; ++i)
#pragma unroll
        for (int j = 0; j < 8; ++j) acc[i][j] = 0.f;

#pragma unroll 2
    for (int d = 0; d < 64; ++d) {
        float a[8], b[8];
        *(float4*)(a)     = *(const float4*)(Qt + d * 128 + ty * 8);
        *(float4*)(a + 4) = *(const float4*)(Qt + d * 128 + ty * 8 + 4);
        *(float4*)(b)     = *(const float4*)(Kt + d * 128 + tx * 8);
        *(float4*)(b + 4) = *(const float4*)(Kt + d * 128 + tx * 8 + 4);
#pragma unroll
        for (int i = 0; i < 8; ++i)
#pragma unroll
            for (int j = 0; j < 8; ++j)
                acc[i][j] = fmaf(a[i], b[j], acc[i][j]);
    }

    float rsum[8];
#pragma unroll
    for (int i = 0; i < 8; ++i) {
        float m = -1e30f;
#pragma unroll
        for (int j = 0; j < 8; ++j) { acc[i][j] *= 0.125f; m = fmaxf(m, acc[i][j]); }
#pragma unroll
        for (int off = 1; off < 16; off <<= 1) m = fmaxf(m, __shfl_xor(m, off, 16));
        float s = 0.f;
#pragma unroll
        for (int j = 0; j < 8; ++j) { float p = expf(acc[i][j] - m); acc[i][j] = p; s += p; }
#pragma unroll
        for (int off = 1; off < 16; off <<= 1) s += __shfl_xor(s, off, 16);
        rsum[i] = s;
    }
    __syncthreads();

#pragma unroll
    for (int j = 0; j < 8; ++j) {
        int c = tx * 8 + j;
        int rb = c * 128 + ((ty * 8) ^ ((tx & 3) << 3));
        *(float4*)(Pt + rb)     = make_float4(acc[0][j], acc[1][j], acc[2][j], acc[3][j]);
        *(float4*)(Pt + rb + 4) = make_float4(acc[4][j], acc[5][j], acc[6][j], acc[7][j]);
    }
    __syncthreads();

    float oacc[8][4];
#pragma unroll
    for (int i = 0; i < 8; ++i)
#pragma unroll
        for (int j = 0; j < 4; ++j) oacc[i][j] = 0.f;

    const int tr = ty;
    const int tc = tx;
#pragma unroll 4
    for (int k = 0; k < 128; ++k) {
        int orig = srow[k];
        float4 b4 = *(const float4*)(Vb + ((size_t)bh * Tz + orig) * 64 + tc * 4);
        int rb = k * 128 + ((tr * 8) ^ (((k >> 3) & 3) << 3));
        float a[8];
        *(float4*)(a)     = *(const float4*)(Pt + rb);
        *(float4*)(a + 4) = *(const float4*)(Pt + rb + 4);
#pragma unroll
        for (int i = 0; i < 8; ++i) {
            oacc[i][0] = fmaf(a[i], b4.x, oacc[i][0]);
            oacc[i][1] = fmaf(a[i], b4.y, oacc[i][1]);
            oacc[i][2] = fmaf(a[i], b4.z, oacc[i][2]);
            oacc[i][3] = fmaf(a[i], b4.w, oacc[i][3]);
        }
    }

    const int bb = bh >> 4;
    const int hh = bh & 15;
#pragma unroll
    for (int i = 0; i < 8; ++i) {
        int r = tr * 8 + i;
        int orig = srow[r];
        float inv = 1.0f / rsum[i];
        *(float4*)(AO + ((size_t)bb * 4096 + orig) * 1024 + hh * 64 + tc * 4) =
            make_float4(oacc[i][0] * inv, oacc[i][1] * inv, oacc[i][2] * inv, oacc[i][3] * inv);
    }
}

// ---------------- output projection ----------------
__global__ __launch_bounds__(256) void k_proj(const float* __restrict__ A,
                                              const float* __restrict__ W,
                                              const float* __restrict__ bias,
                                              float* __restrict__ Cout)
{
    __shared__ float As[16][128];
    __shared__ float Bs[16][128];
    const int tid = threadIdx.x;
    const int n0 = blockIdx.x * 128;
    const int m0 = blockIdx.y * 128;
    const int tx = tid & 15, ty = tid >> 4;
    float acc[8][8];
#pragma unroll
    for (int i = 0; i < 8; ++i)
#pragma unroll
        for (int j = 0; j < 8; ++j) acc[i][j] = 0.f;

    for (int kt = 0; kt < 1024; kt += 16) {
#pragma unroll
        for (int i = 0; i < 2; ++i) {
            int idx = tid * 2 + i;
            int row = idx >> 2;
            int kq = idx & 3;
            float4 a4 = *(const float4*)(A + (size_t)(m0 + row) * 1024 + kt + kq * 4);
            As[kq * 4 + 0][row] = a4.x;
            As[kq * 4 + 1][row] = a4.y;
            As[kq * 4 + 2][row] = a4.z;
            As[kq * 4 + 3][row] = a4.w;
        }
#pragma unroll
        for (int i = 0; i < 2; ++i) {
            int idx = tid * 2 + i;
            int rr = idx >> 5;
            int c4 = idx & 31;
            *(float4*)(&Bs[rr][c4 * 4]) = *(const float4*)(W + (size_t)(kt + rr) * 1024 + n0 + c4 * 4);
        }
        __syncthreads();
#pragma unroll
        for (int kk = 0; kk < 16; ++kk) {
            float a[8], b[8];
            *(float4*)(a)     = *(const float4*)(&As[kk][ty * 8]);
            *(float4*)(a + 4) = *(const float4*)(&As[kk][ty * 8 + 4]);
            *(float4*)(b)     = *(const float4*)(&Bs[kk][tx * 8]);
            *(float4*)(b + 4) = *(const float4*)(&Bs[kk][tx * 8 + 4]);
#pragma unroll
            for (int i = 0; i < 8; ++i)
#pragma unroll
                for (int j = 0; j < 8; ++j)
                    acc[i][j] = fmaf(a[i], b[j], acc[i][j]);
        }
        __syncthreads();
    }
    float bv[8];
#pragma unroll
    for (int j = 0; j < 8; ++j) bv[j] = bias[n0 + tx * 8 + j];
#pragma unroll
    for (int i = 0; i < 8; ++i) {
        int r = m0 + ty * 8 + i;
        float* dst = Cout + (size_t)r * 1024 + n0 + tx * 8;
        *(float4*)(dst)     = make_float4(acc[i][0] + bv[0], acc[i][1] + bv[1], acc[i][2] + bv[2], acc[i][3] + bv[3]);
        *(float4*)(dst + 4) = make_float4(acc[i][4] + bv[4], acc[i][5] + bv[5], acc[i][6] + bv[6], acc[i][7] + bv[7]);
    }
}

extern "C" void kernel_launch(void* const* d_in, const int* in_sizes, int n_in,
                              void* d_out, int out_size, void* d_ws, size_t ws_size,
                              hipStream_t stream)
{
    const float* x      = (const float*)d_in[0];
    const float* W_attn = (const float*)d_in[1];
    const float* b_attn = (const float*)d_in[2];
    const float* W_proj = (const float*)d_in[3];
    const float* b_proj = (const float*)d_in[4];
    const float* R      = (const float*)d_in[5];
    float* out = (float*)d_out;

    // Workspace (204 MB). x_hi/x_lo alias AO (dead by k_attn); V aliases d_out.
    char* ws = (char*)d_ws;
    const size_t MB = 1024 * 1024;
    float*          tbl  = (float*)(ws);                    // 2 MB
    float*          Qb   = (float*)(ws + 2 * MB);           // 64 MB
    float*          Kb   = (float*)(ws + 66 * MB);          // 64 MB
    float*          AO   = (float*)(ws + 130 * MB);         // 64 MB (aliases xh/xl)
    unsigned short* xh   = (unsigned short*)(ws + 130 * MB);// 32 MB
    unsigned short* xl   = (unsigned short*)(ws + 162 * MB);// 32 MB
    int*            bidx = (int*)(ws + 194 * MB);           // 1 MB
    int*            sidx = (int*)(ws + 195 * MB);           // 1 MB
    unsigned short* wth  = (unsigned short*)(ws + 196 * MB);// 4 MB
    unsigned short* wtl  = (unsigned short*)(ws + 200 * MB);// 4 MB
    float*          Vb   = (float*)d_out;                   // scratch until k_proj

    k_trig  <<<dim3(16),       dim3(256), 0, stream>>>(tbl);
    k_cvtA  <<<dim3(16384),    dim3(256), 0, stream>>>(x, xh, xl);
    k_cvtB  <<<dim3(32, 16),   dim3(256), 0, stream>>>(W_attn, wth, wtl);
    k_qkv   <<<dim3(8, 128),   dim3(256), 0, stream>>>(x, W_attn, b_attn, tbl, Qb, Kb, Vb);
    k_kv    <<<dim3(16, 128),  dim3(256), 0, stream>>>(xh, xl, wth, wtl, b_attn, tbl, Kb, Vb);
    k_bucket<<<dim3(4096),     dim3(64),  0, stream>>>(Qb, R, bidx);
    k_sort  <<<dim3(64),       dim3(64),  0, stream>>>(bidx, sidx);
    k_attn  <<<dim3(32, 64),   dim3(256), 0, stream>>>(Qb, Kb, Vb, sidx, AO);
    k_proj  <<<dim3(8, 128),   dim3(256), 0, stream>>>(AO, W_proj, b_proj, out);
}

// Round 4
// 1493.604 us; speedup vs baseline: 1.4922x; 1.1743x over previous
//
#include <hip/hip_runtime.h>
#include <math.h>

#define Bz 4
#define Tz 4096
#define Dz 1024
#define Hz 16
#define HDz 64
#define BHz 64
#define Mz 16384

typedef __attribute__((ext_vector_type(8))) short short8;
typedef __attribute__((ext_vector_type(8))) __bf16 bf16x8;
typedef __attribute__((ext_vector_type(4))) float floatx4;

__device__ inline unsigned short f2bf(float f) {
    unsigned u = __float_as_uint(f);
    u = (u + 0x7fffu + ((u >> 16) & 1u)) >> 16;   // RNE; finite data only
    return (unsigned short)u;
}
__device__ inline float bf2f(unsigned short h) {
    return __uint_as_float(((unsigned)h) << 16);
}

// ---------------- trig table ----------------
__global__ __launch_bounds__(256) void k_trig(float* __restrict__ tbl) {
    int t = blockIdx.x * 256 + threadIdx.x;
    float ft = (float)t;
    for (int j = 0; j < 64; ++j) {
        int kidx = (j < 32) ? j : (j - 32);
        double e = (double)(2 * kidx) / 64.0;
        float p = (float)pow(10000.0, e);
        float invf = 1.0f / p;
        float arg = ft * invf;
        tbl[t * 128 + j * 2 + 0] = cosf(arg);
        tbl[t * 128 + j * 2 + 1] = sinf(arg);
    }
}

// ---------------- split fp32 x -> bf16 hi/lo ----------------
__global__ __launch_bounds__(256) void k_cvtA(const float* __restrict__ x,
                                              unsigned short* __restrict__ xh,
                                              unsigned short* __restrict__ xl)
{
    size_t i4 = (size_t)blockIdx.x * 256 + threadIdx.x;
    float4 v = *(const float4*)(x + i4 * 4);
    ushort4 h, l;
    h.x = f2bf(v.x); l.x = f2bf(v.x - bf2f(h.x));
    h.y = f2bf(v.y); l.y = f2bf(v.y - bf2f(h.y));
    h.z = f2bf(v.z); l.z = f2bf(v.z - bf2f(h.z));
    h.w = f2bf(v.w); l.w = f2bf(v.w - bf2f(h.w));
    *(ushort4*)(xh + i4 * 4) = h;
    *(ushort4*)(xl + i4 * 4) = l;
}

// ---------------- transpose+split W_attn K/V cols: Wt[n][k] = W[k][1024+n] ----------------
__global__ __launch_bounds__(256) void k_cvtB(const float* __restrict__ W,
                                              unsigned short* __restrict__ wh,
                                              unsigned short* __restrict__ wl)
{
    __shared__ float tile[64][65];
    const int n0 = blockIdx.x * 64;
    const int k0 = blockIdx.y * 64;
    const int tid = threadIdx.x;
#pragma unroll
    for (int i = 0; i < 16; ++i) {
        int flat = i * 256 + tid;
        int kr = flat >> 6, nc = flat & 63;
        tile[kr][nc] = W[(size_t)(k0 + kr) * 3072 + 1024 + n0 + nc];
    }
    __syncthreads();
#pragma unroll
    for (int i = 0; i < 16; ++i) {
        int flat = i * 256 + tid;
        int nr = flat >> 6, kc = flat & 63;
        float v = tile[kc][nr];
        unsigned short h = f2bf(v);
        wh[(size_t)(n0 + nr) * 1024 + k0 + kc] = h;
        wl[(size_t)(n0 + nr) * 1024 + k0 + kc] = f2bf(v - bf2f(h));
    }
}

// ---------------- transpose+split W_proj: Wt[n][k] = W[k][n] ----------------
__global__ __launch_bounds__(256) void k_cvtP(const float* __restrict__ W,
                                              unsigned short* __restrict__ wh,
                                              unsigned short* __restrict__ wl)
{
    __shared__ float tile[64][65];
    const int n0 = blockIdx.x * 64;   // 16
    const int k0 = blockIdx.y * 64;   // 16
    const int tid = threadIdx.x;
#pragma unroll
    for (int i = 0; i < 16; ++i) {
        int flat = i * 256 + tid;
        int kr = flat >> 6, nc = flat & 63;
        tile[kr][nc] = W[(size_t)(k0 + kr) * 1024 + n0 + nc];
    }
    __syncthreads();
#pragma unroll
    for (int i = 0; i < 16; ++i) {
        int flat = i * 256 + tid;
        int nr = flat >> 6, kc = flat & 63;
        float v = tile[kc][nr];
        unsigned short h = f2bf(v);
        wh[(size_t)(n0 + nr) * 1024 + k0 + kc] = h;
        wl[(size_t)(n0 + nr) * 1024 + k0 + kc] = f2bf(v - bf2f(h));
    }
}

// ---------------- Q-only fp32 GEMM (bit-identical, grid x=8) -------------
__global__ __launch_bounds__(256) void k_qkv(const float* __restrict__ A,
                                             const float* __restrict__ W,
                                             const float* __restrict__ bias,
                                             const float* __restrict__ tbl,
                                             float* __restrict__ Qb,
                                             float* __restrict__ Kb,
                                             float* __restrict__ Vb)
{
    __shared__ float As[16][128];
    __shared__ float Bs[16][128];
    const int tid = threadIdx.x;
    const int n0 = blockIdx.x * 128;
    const int m0 = blockIdx.y * 128;
    const int tx = tid & 15, ty = tid >> 4;
    float acc[8][8];
#pragma unroll
    for (int i = 0; i < 8; ++i)
#pragma unroll
        for (int j = 0; j < 8; ++j) acc[i][j] = 0.f;

    for (int kt = 0; kt < 1024; kt += 16) {
#pragma unroll
        for (int i = 0; i < 2; ++i) {
            int idx = tid * 2 + i;
            int row = idx >> 2;
            int kq = idx & 3;
            float4 a4 = *(const float4*)(A + (size_t)(m0 + row) * 1024 + kt + kq * 4);
            As[kq * 4 + 0][row] = a4.x;
            As[kq * 4 + 1][row] = a4.y;
            As[kq * 4 + 2][row] = a4.z;
            As[kq * 4 + 3][row] = a4.w;
        }
#pragma unroll
        for (int i = 0; i < 2; ++i) {
            int idx = tid * 2 + i;
            int rr = idx >> 5;
            int c4 = idx & 31;
            *(float4*)(&Bs[rr][c4 * 4]) = *(const float4*)(W + (size_t)(kt + rr) * 3072 + n0 + c4 * 4);
        }
        __syncthreads();
#pragma unroll
        for (int kk = 0; kk < 16; ++kk) {
            float a[8], b[8];
            *(float4*)(a)     = *(const float4*)(&As[kk][ty * 8]);
            *(float4*)(a + 4) = *(const float4*)(&As[kk][ty * 8 + 4]);
            *(float4*)(b)     = *(const float4*)(&Bs[kk][tx * 8]);
            *(float4*)(b + 4) = *(const float4*)(&Bs[kk][tx * 8 + 4]);
#pragma unroll
            for (int i = 0; i < 8; ++i)
#pragma unroll
                for (int j = 0; j < 8; ++j)
                    acc[i][j] = fmaf(a[i], b[j], acc[i][j]);
        }
        __syncthreads();
    }
    const int cbase = n0 + tx * 8;
    const int part = cbase >> 10;        // always 0 (Q)
    const int cc = cbase & 1023;
    const int h = cc >> 6;
    const int dbase = cc & 63;
    const int bb = m0 >> 12;
    const int tbase = (m0 & 4095) + ty * 8;
    float bv[8];
#pragma unroll
    for (int j = 0; j < 8; ++j) bv[j] = bias[cbase + j];

    if (part == 2) {
#pragma unroll
        for (int i = 0; i < 8; ++i) {
            int t = tbase + i;
            float* dst = Vb + ((size_t)(bb * 16 + h) * 4096 + t) * 64 + dbase;
            *(float4*)(dst)     = make_float4(acc[i][0] + bv[0], acc[i][1] + bv[1], acc[i][2] + bv[2], acc[i][3] + bv[3]);
            *(float4*)(dst + 4) = make_float4(acc[i][4] + bv[4], acc[i][5] + bv[5], acc[i][6] + bv[6], acc[i][7] + bv[7]);
        }
    } else {
        float* DST = (part == 0) ? Qb : Kb;
#pragma unroll
        for (int i = 0; i < 8; ++i) {
            int t = tbase + i;
            const float4* tb = (const float4*)(tbl + t * 128 + dbase * 2);
            float o[8];
#pragma unroll
            for (int jp = 0; jp < 4; ++jp) {
                float4 cs = tb[jp];
                float ae = acc[i][jp * 2]     + bv[jp * 2];
                float ao = acc[i][jp * 2 + 1] + bv[jp * 2 + 1];
                o[jp * 2]     = ae * cs.x - ao * cs.y;
                o[jp * 2 + 1] = ao * cs.z + ae * cs.w;
            }
            float* dst = DST + ((size_t)(bb * 16 + h) * 4096 + t) * 64 + dbase;
            *(float4*)(dst)     = make_float4(o[0], o[1], o[2], o[3]);
            *(float4*)(dst + 4) = make_float4(o[4], o[5], o[6], o[7]);
        }
    }
}

// ---------------- K,V via split-bf16 MFMA ----------------
__global__ __launch_bounds__(256) void k_kv(const unsigned short* __restrict__ xh,
                                            const unsigned short* __restrict__ xl,
                                            const unsigned short* __restrict__ wh,
                                            const unsigned short* __restrict__ wl,
                                            const float* __restrict__ bias,
                                            const float* __restrict__ tbl,
                                            float* __restrict__ Kb,
                                            float* __restrict__ Vb)
{
    __shared__ unsigned short Ah[128 * 32], Al[128 * 32], Bh[128 * 32], Bl[128 * 32];
    const int tid = threadIdx.x;
    const int lane = tid & 63, wv = tid >> 6;
    const int n0 = blockIdx.x * 128;
    const int m0 = blockIdx.y * 128;
    const int wm = (wv & 1) * 64, wn = (wv >> 1) * 64;
    const int sr = tid >> 2, sc = tid & 3;
    const int fr = lane & 15, fq = lane >> 4;

    floatx4 acc[4][4];
#pragma unroll
    for (int i = 0; i < 4; ++i)
#pragma unroll
        for (int j = 0; j < 4; ++j) acc[i][j] = (floatx4){0.f, 0.f, 0.f, 0.f};

    for (int kt = 0; kt < 1024; kt += 32) {
        __syncthreads();
#pragma unroll
        for (int s = 0; s < 2; ++s) {
            int row = s * 64 + sr;
            size_t ga = (size_t)(m0 + row) * 1024 + kt + sc * 8;
            size_t gb = (size_t)(n0 + row) * 1024 + kt + sc * 8;
            *(short8*)(&Ah[row * 32 + sc * 8]) = *(const short8*)(xh + ga);
            *(short8*)(&Al[row * 32 + sc * 8]) = *(const short8*)(xl + ga);
            *(short8*)(&Bh[row * 32 + sc * 8]) = *(const short8*)(wh + gb);
            *(short8*)(&Bl[row * 32 + sc * 8]) = *(const short8*)(wl + gb);
        }
        __syncthreads();

        bf16x8 afh[4], afl[4], bfh[4], bfl[4];
#pragma unroll
        for (int i = 0; i < 4; ++i) {
            afh[i] = __builtin_bit_cast(bf16x8, *(const short8*)(&Ah[(wm + i * 16 + fr) * 32 + fq * 8]));
            afl[i] = __builtin_bit_cast(bf16x8, *(const short8*)(&Al[(wm + i * 16 + fr) * 32 + fq * 8]));
            bfh[i] = __builtin_bit_cast(bf16x8, *(const short8*)(&Bh[(wn + i * 16 + fr) * 32 + fq * 8]));
            bfl[i] = __builtin_bit_cast(bf16x8, *(const short8*)(&Bl[(wn + i * 16 + fr) * 32 + fq * 8]));
        }
#pragma unroll
        for (int i = 0; i < 4; ++i)
#pragma unroll
            for (int j = 0; j < 4; ++j) {
                acc[i][j] = __builtin_amdgcn_mfma_f32_16x16x32_bf16(afh[i], bfh[j], acc[i][j], 0, 0, 0);
                acc[i][j] = __builtin_amdgcn_mfma_f32_16x16x32_bf16(afh[i], bfl[j], acc[i][j], 0, 0, 0);
                acc[i][j] = __builtin_amdgcn_mfma_f32_16x16x32_bf16(afl[i], bfh[j], acc[i][j], 0, 0, 0);
            }
    }

#pragma unroll
    for (int j = 0; j < 4; ++j) {
        int nn = n0 + wn + j * 16 + fr;
        float bv = bias[1024 + nn];
#pragma unroll
        for (int i = 0; i < 4; ++i) {
#pragma unroll
            for (int r = 0; r < 4; ++r) {
                int mm = m0 + wm + i * 16 + fq * 4 + r;
                int t = mm & 4095, bb = mm >> 12;
                float y = acc[i][j][r] + bv;
                if (nn < 1024) {
                    int h = nn >> 6, d = nn & 63;
                    float part = __shfl_xor(y, 1);
                    float c = tbl[t * 128 + d * 2];
                    float s = tbl[t * 128 + d * 2 + 1];
                    float o = (d & 1) ? fmaf(part, s, y * c) : fmaf(-part, s, y * c);
                    Kb[((size_t)(bb * 16 + h) * 4096 + t) * 64 + d] = o;
                } else {
                    int nv = nn - 1024;
                    int h = nv >> 6, d = nv & 63;
                    Vb[((size_t)(bb * 16 + h) * 4096 + t) * 64 + d] = y;
                }
            }
        }
    }
}

// ---------------- bucket argmax ----------------
__global__ __launch_bounds__(64) void k_bucket(const float* __restrict__ Q,
                                               const float* __restrict__ R,
                                               int* __restrict__ bidx)
{
    __shared__ float Qs[64][65];
    __shared__ float Rs[64][32];
    const int tid = threadIdx.x;
    const int g0 = blockIdx.x * 64;
    const int bh = g0 >> 12;
    const int t0 = g0 & 4095;
#pragma unroll
    for (int m = 0; m < 32; ++m) Rs[tid][m] = R[tid * 64 + m];
    const float* qbase = Q + ((size_t)bh * Tz + t0) * 64;
    for (int r = 0; r < 64; ++r) Qs[r][tid] = qbase[(size_t)r * 64 + tid];
    __syncthreads();

    float s[32];
#pragma unroll
    for (int m = 0; m < 32; ++m) s[m] = 0.f;
    for (int d = 0; d < 64; ++d) {
        float qd = Qs[tid][d];
#pragma unroll
        for (int m4 = 0; m4 < 8; ++m4) {
            float4 r4 = *(const float4*)(&Rs[d][m4 * 4]);
            s[m4 * 4 + 0] = fmaf(qd, r4.x, s[m4 * 4 + 0]);
            s[m4 * 4 + 1] = fmaf(qd, r4.y, s[m4 * 4 + 1]);
            s[m4 * 4 + 2] = fmaf(qd, r4.z, s[m4 * 4 + 2]);
            s[m4 * 4 + 3] = fmaf(qd, r4.w, s[m4 * 4 + 3]);
        }
    }
    float best = s[0];
    int bi = 0;
#pragma unroll
    for (int m = 1; m < 64; ++m) {
        float v = (m < 32) ? s[m] : -s[m - 32];
        if (v > best) { best = v; bi = m; }
    }
    bidx[g0 + tid] = bi;
}

// ---------------- stable counting sort ----------------
__global__ __launch_bounds__(64) void k_sort(const int* __restrict__ bidx,
                                             int* __restrict__ sidx)
{
    __shared__ int lb[4096];
    __shared__ int ls[4096];
    const int tid = threadIdx.x;
    const int bh = blockIdx.x;
    const int* brow = bidx + (size_t)bh * 4096;
    for (int i = tid; i < 4096; i += 64) lb[i] = brow[i];
    __syncthreads();
    int cnt = 0;
    for (int i = 0; i < 4096; ++i) cnt += (lb[i] == tid);
    int run = cnt;
#pragma unroll
    for (int off = 1; off < 64; off <<= 1) {
        int n = __shfl_up(run, off, 64);
        if (tid >= off) run += n;
    }
    int pos = run - cnt;
    for (int i = 0; i < 4096; ++i) {
        if (lb[i] == tid) { ls[pos] = i; ++pos; }
    }
    __syncthreads();
    int* srow = sidx + (size_t)bh * 4096;
    for (int i = tid; i < 4096; i += 64) srow[i] = ls[i];
}

// ---------------- chunked attention; writes AO as bf16 hi/lo --------------
__global__ __launch_bounds__(256) void k_attn(const float* __restrict__ Q,
                                              const float* __restrict__ Kb,
                                              const float* __restrict__ Vb,
                                              const int* __restrict__ sidx,
                                              unsigned short* __restrict__ AOh,
                                              unsigned short* __restrict__ AOl)
{
    __shared__ float smem[16384];
    float* Qt = smem;
    float* Kt = smem + 8192;
    float* Pt = smem;
    const int bh = blockIdx.y;
    const int ch = blockIdx.x;
    const int tid = threadIdx.x;
    const int* srow = sidx + (size_t)bh * Tz + ch * 128;

    {
        int r = tid >> 1;
        int ds = (tid & 1) * 32;
        int orig = srow[r];
        const float* qp = Q  + ((size_t)bh * Tz + orig) * 64 + ds;
        const float* kp = Kb + ((size_t)bh * Tz + orig) * 64 + ds;
#pragma unroll
        for (int j4 = 0; j4 < 8; ++j4) {
            float4 q4 = *(const float4*)(qp + j4 * 4);
            float4 k4 = *(const float4*)(kp + j4 * 4);
            int d = ds + j4 * 4;
            Qt[(d + 0) * 128 + r] = q4.x; Qt[(d + 1) * 128 + r] = q4.y;
            Qt[(d + 2) * 128 + r] = q4.z; Qt[(d + 3) * 128 + r] = q4.w;
            Kt[(d + 0) * 128 + r] = k4.x; Kt[(d + 1) * 128 + r] = k4.y;
            Kt[(d + 2) * 128 + r] = k4.z; Kt[(d + 3) * 128 + r] = k4.w;
        }
    }
    __syncthreads();

    const int tx = tid & 15, ty = tid >> 4;
    float acc[8][8];
#pragma unroll
    for (int i = 0; i < 8; ++i)
#pragma unroll
        for (int j = 0; j < 8; ++j) acc[i][j] = 0.f;

#pragma unroll 2
    for (int d = 0; d < 64; ++d) {
        float a[8], b[8];
        *(float4*)(a)     = *(const float4*)(Qt + d * 128 + ty * 8);
        *(float4*)(a + 4) = *(const float4*)(Qt + d * 128 + ty * 8 + 4);
        *(float4*)(b)     = *(const float4*)(Kt + d * 128 + tx * 8);
        *(float4*)(b + 4) = *(const float4*)(Kt + d * 128 + tx * 8 + 4);
#pragma unroll
        for (int i = 0; i < 8; ++i)
#pragma unroll
            for (int j = 0; j < 8; ++j)
                acc[i][j] = fmaf(a[i], b[j], acc[i][j]);
    }

    float rsum[8];
#pragma unroll
    for (int i = 0; i < 8; ++i) {
        float m = -1e30f;
#pragma unroll
        for (int j = 0; j < 8; ++j) { acc[i][j] *= 0.125f; m = fmaxf(m, acc[i][j]); }
#pragma unroll
        for (int off = 1; off < 16; off <<= 1) m = fmaxf(m, __shfl_xor(m, off, 16));
        float s = 0.f;
#pragma unroll
        for (int j = 0; j < 8; ++j) { float p = expf(acc[i][j] - m); acc[i][j] = p; s += p; }
#pragma unroll
        for (int off = 1; off < 16; off <<= 1) s += __shfl_xor(s, off, 16);
        rsum[i] = s;
    }
    __syncthreads();

#pragma unroll
    for (int j = 0; j < 8; ++j) {
        int c = tx * 8 + j;
        int rb = c * 128 + ((ty * 8) ^ ((tx & 3) << 3));
        *(float4*)(Pt + rb)     = make_float4(acc[0][j], acc[1][j], acc[2][j], acc[3][j]);
        *(float4*)(Pt + rb + 4) = make_float4(acc[4][j], acc[5][j], acc[6][j], acc[7][j]);
    }
    __syncthreads();

    float oacc[8][4];
#pragma unroll
    for (int i = 0; i < 8; ++i)
#pragma unroll
        for (int j = 0; j < 4; ++j) oacc[i][j] = 0.f;

    const int tr = ty;
    const int tc = tx;
#pragma unroll 4
    for (int k = 0; k < 128; ++k) {
        int orig = srow[k];
        float4 b4 = *(const float4*)(Vb + ((size_t)bh * Tz + orig) * 64 + tc * 4);
        int rb = k * 128 + ((tr * 8) ^ (((k >> 3) & 3) << 3));
        float a[8];
        *(float4*)(a)     = *(const float4*)(Pt + rb);
        *(float4*)(a + 4) = *(const float4*)(Pt + rb + 4);
#pragma unroll
        for (int i = 0; i < 8; ++i) {
            oacc[i][0] = fmaf(a[i], b4.x, oacc[i][0]);
            oacc[i][1] = fmaf(a[i], b4.y, oacc[i][1]);
            oacc[i][2] = fmaf(a[i], b4.z, oacc[i][2]);
            oacc[i][3] = fmaf(a[i], b4.w, oacc[i][3]);
        }
    }

    const int bb = bh >> 4;
    const int hh = bh & 15;
#pragma unroll
    for (int i = 0; i < 8; ++i) {
        int r = tr * 8 + i;
        int orig = srow[r];
        float inv = 1.0f / rsum[i];
        float o0 = oacc[i][0] * inv, o1 = oacc[i][1] * inv;
        float o2 = oacc[i][2] * inv, o3 = oacc[i][3] * inv;
        ushort4 h4, l4;
        h4.x = f2bf(o0); l4.x = f2bf(o0 - bf2f(h4.x));
        h4.y = f2bf(o1); l4.y = f2bf(o1 - bf2f(h4.y));
        h4.z = f2bf(o2); l4.z = f2bf(o2 - bf2f(h4.z));
        h4.w = f2bf(o3); l4.w = f2bf(o3 - bf2f(h4.w));
        size_t base = ((size_t)bb * 4096 + orig) * 1024 + hh * 64 + tc * 4;
        *(ushort4*)(AOh + base) = h4;
        *(ushort4*)(AOl + base) = l4;
    }
}

// ---------------- output projection via split-bf16 MFMA ----------------
__global__ __launch_bounds__(256) void k_proj(const unsigned short* __restrict__ ah,
                                              const unsigned short* __restrict__ al,
                                              const unsigned short* __restrict__ wh,
                                              const unsigned short* __restrict__ wl,
                                              const float* __restrict__ bias,
                                              float* __restrict__ Cout)
{
    __shared__ unsigned short Ah[128 * 32], Al[128 * 32], Bh[128 * 32], Bl[128 * 32];
    const int tid = threadIdx.x;
    const int lane = tid & 63, wv = tid >> 6;
    const int n0 = blockIdx.x * 128;   // 8 blocks
    const int m0 = blockIdx.y * 128;   // 128 blocks
    const int wm = (wv & 1) * 64, wn = (wv >> 1) * 64;
    const int sr = tid >> 2, sc = tid & 3;
    const int fr = lane & 15, fq = lane >> 4;

    floatx4 acc[4][4];
#pragma unroll
    for (int i = 0; i < 4; ++i)
#pragma unroll
        for (int j = 0; j < 4; ++j) acc[i][j] = (floatx4){0.f, 0.f, 0.f, 0.f};

    for (int kt = 0; kt < 1024; kt += 32) {
        __syncthreads();
#pragma unroll
        for (int s = 0; s < 2; ++s) {
            int row = s * 64 + sr;
            size_t ga = (size_t)(m0 + row) * 1024 + kt + sc * 8;
            size_t gb = (size_t)(n0 + row) * 1024 + kt + sc * 8;
            *(short8*)(&Ah[row * 32 + sc * 8]) = *(const short8*)(ah + ga);
            *(short8*)(&Al[row * 32 + sc * 8]) = *(const short8*)(al + ga);
            *(short8*)(&Bh[row * 32 + sc * 8]) = *(const short8*)(wh + gb);
            *(short8*)(&Bl[row * 32 + sc * 8]) = *(const short8*)(wl + gb);
        }
        __syncthreads();

        bf16x8 afh[4], afl[4], bfh[4], bfl[4];
#pragma unroll
        for (int i = 0; i < 4; ++i) {
            afh[i] = __builtin_bit_cast(bf16x8, *(const short8*)(&Ah[(wm + i * 16 + fr) * 32 + fq * 8]));
            afl[i] = __builtin_bit_cast(bf16x8, *(const short8*)(&Al[(wm + i * 16 + fr) * 32 + fq * 8]));
            bfh[i] = __builtin_bit_cast(bf16x8, *(const short8*)(&Bh[(wn + i * 16 + fr) * 32 + fq * 8]));
            bfl[i] = __builtin_bit_cast(bf16x8, *(const short8*)(&Bl[(wn + i * 16 + fr) * 32 + fq * 8]));
        }
#pragma unroll
        for (int i = 0; i < 4; ++i)
#pragma unroll
            for (int j = 0; j < 4; ++j) {
                acc[i][j] = __builtin_amdgcn_mfma_f32_16x16x32_bf16(afh[i], bfh[j], acc[i][j], 0, 0, 0);
                acc[i][j] = __builtin_amdgcn_mfma_f32_16x16x32_bf16(afh[i], bfl[j], acc[i][j], 0, 0, 0);
                acc[i][j] = __builtin_amdgcn_mfma_f32_16x16x32_bf16(afl[i], bfh[j], acc[i][j], 0, 0, 0);
            }
    }

#pragma unroll
    for (int j = 0; j < 4; ++j) {
        int nn = n0 + wn + j * 16 + fr;
        float bv = bias[nn];
#pragma unroll
        for (int i = 0; i < 4; ++i) {
#pragma unroll
            for (int r = 0; r < 4; ++r) {
                int mm = m0 + wm + i * 16 + fq * 4 + r;
                Cout[(size_t)mm * 1024 + nn] = acc[i][j][r] + bv;
            }
        }
    }
}

extern "C" void kernel_launch(void* const* d_in, const int* in_sizes, int n_in,
                              void* d_out, int out_size, void* d_ws, size_t ws_size,
                              hipStream_t stream)
{
    const float* x      = (const float*)d_in[0];
    const float* W_attn = (const float*)d_in[1];
    const float* b_attn = (const float*)d_in[2];
    const float* W_proj = (const float*)d_in[3];
    const float* b_proj = (const float*)d_in[4];
    const float* R      = (const float*)d_in[5];
    float* out = (float*)d_out;

    // Workspace (204 MB). xh/xl alias AOh/AOl (xh dead after k_kv, AO written by k_attn).
    // wph/wpl reuse wth/wtl slots (dead after k_kv; k_cvtP launched after k_kv).
    // V aliases d_out (dead once k_proj writes).
    char* ws = (char*)d_ws;
    const size_t MB = 1024 * 1024;
    float*          tbl  = (float*)(ws);                    // 2 MB
    float*          Qb   = (float*)(ws + 2 * MB);           // 64 MB
    float*          Kb   = (float*)(ws + 66 * MB);          // 64 MB
    unsigned short* xh   = (unsigned short*)(ws + 130 * MB);// 32 MB
    unsigned short* xl   = (unsigned short*)(ws + 162 * MB);// 32 MB
    unsigned short* AOh  = (unsigned short*)(ws + 130 * MB);// 32 MB (alias xh)
    unsigned short* AOl  = (unsigned short*)(ws + 162 * MB);// 32 MB (alias xl)
    int*            bidx = (int*)(ws + 194 * MB);           // 1 MB
    int*            sidx = (int*)(ws + 195 * MB);           // 1 MB
    unsigned short* wth  = (unsigned short*)(ws + 196 * MB);// 4 MB
    unsigned short* wtl  = (unsigned short*)(ws + 200 * MB);// 4 MB
    unsigned short* wph  = (unsigned short*)(ws + 196 * MB);// 2 MB (alias wth, after k_kv)
    unsigned short* wpl  = (unsigned short*)(ws + 200 * MB);// 2 MB (alias wtl, after k_kv)
    float*          Vb   = (float*)d_out;                   // scratch until k_proj

    k_trig  <<<dim3(16),       dim3(256), 0, stream>>>(tbl);
    k_cvtA  <<<dim3(16384),    dim3(256), 0, stream>>>(x, xh, xl);
    k_cvtB  <<<dim3(32, 16),   dim3(256), 0, stream>>>(W_attn, wth, wtl);
    k_qkv   <<<dim3(8, 128),   dim3(256), 0, stream>>>(x, W_attn, b_attn, tbl, Qb, Kb, Vb);
    k_kv    <<<dim3(16, 128),  dim3(256), 0, stream>>>(xh, xl, wth, wtl, b_attn, tbl, Kb, Vb);
    k_cvtP  <<<dim3(16, 16),   dim3(256), 0, stream>>>(W_proj, wph, wpl);
    k_bucket<<<dim3(4096),     dim3(64),  0, stream>>>(Qb, R, bidx);
    k_sort  <<<dim3(64),       dim3(64),  0, stream>>>(bidx, sidx);
    k_attn  <<<dim3(32, 64),   dim3(256), 0, stream>>>(Qb, Kb, Vb, sidx, AOh, AOl);
    k_proj  <<<dim3(8, 128),   dim3(256), 0, stream>>>(AOh, AOl, wph, wpl, b_proj, out);
}

// Round 5
// 1378.678 us; speedup vs baseline: 1.6166x; 1.0834x over previous
//
#include <hip/hip_runtime.h>
#include <math.h>

#define Bz 4
#define Tz 4096
#define Dz 1024
#define Hz 16
#define HDz 64
#define BHz 64
#define Mz 16384

typedef __attribute__((ext_vector_type(8))) short short8;
typedef __attribute__((ext_vector_type(8))) __bf16 bf16x8;
typedef __attribute__((ext_vector_type(4))) float floatx4;

__device__ inline unsigned short f2bf(float f) {
    unsigned u = __float_as_uint(f);
    u = (u + 0x7fffu + ((u >> 16) & 1u)) >> 16;   // RNE; finite data only
    return (unsigned short)u;
}
__device__ inline float bf2f(unsigned short h) {
    return __uint_as_float(((unsigned)h) << 16);
}

// ---------------- trig table ----------------
__global__ __launch_bounds__(256) void k_trig(float* __restrict__ tbl) {
    int t = blockIdx.x * 256 + threadIdx.x;
    float ft = (float)t;
    for (int j = 0; j < 64; ++j) {
        int kidx = (j < 32) ? j : (j - 32);
        double e = (double)(2 * kidx) / 64.0;
        float p = (float)pow(10000.0, e);
        float invf = 1.0f / p;
        float arg = ft * invf;
        tbl[t * 128 + j * 2 + 0] = cosf(arg);
        tbl[t * 128 + j * 2 + 1] = sinf(arg);
    }
}

// ---------------- split fp32 x -> bf16 hi/lo ----------------
__global__ __launch_bounds__(256) void k_cvtA(const float* __restrict__ x,
                                              unsigned short* __restrict__ xh,
                                              unsigned short* __restrict__ xl)
{
    size_t i4 = (size_t)blockIdx.x * 256 + threadIdx.x;
    float4 v = *(const float4*)(x + i4 * 4);
    ushort4 h, l;
    h.x = f2bf(v.x); l.x = f2bf(v.x - bf2f(h.x));
    h.y = f2bf(v.y); l.y = f2bf(v.y - bf2f(h.y));
    h.z = f2bf(v.z); l.z = f2bf(v.z - bf2f(h.z));
    h.w = f2bf(v.w); l.w = f2bf(v.w - bf2f(h.w));
    *(ushort4*)(xh + i4 * 4) = h;
    *(ushort4*)(xl + i4 * 4) = l;
}

// ---------------- transpose+split W_attn K/V cols ----------------
__global__ __launch_bounds__(256) void k_cvtB(const float* __restrict__ W,
                                              unsigned short* __restrict__ wh,
                                              unsigned short* __restrict__ wl)
{
    __shared__ float tile[64][65];
    const int n0 = blockIdx.x * 64;
    const int k0 = blockIdx.y * 64;
    const int tid = threadIdx.x;
#pragma unroll
    for (int i = 0; i < 16; ++i) {
        int flat = i * 256 + tid;
        int kr = flat >> 6, nc = flat & 63;
        tile[kr][nc] = W[(size_t)(k0 + kr) * 3072 + 1024 + n0 + nc];
    }
    __syncthreads();
#pragma unroll
    for (int i = 0; i < 16; ++i) {
        int flat = i * 256 + tid;
        int nr = flat >> 6, kc = flat & 63;
        float v = tile[kc][nr];
        unsigned short h = f2bf(v);
        wh[(size_t)(n0 + nr) * 1024 + k0 + kc] = h;
        wl[(size_t)(n0 + nr) * 1024 + k0 + kc] = f2bf(v - bf2f(h));
    }
}

// ---------------- transpose+split W_proj ----------------
__global__ __launch_bounds__(256) void k_cvtP(const float* __restrict__ W,
                                              unsigned short* __restrict__ wh,
                                              unsigned short* __restrict__ wl)
{
    __shared__ float tile[64][65];
    const int n0 = blockIdx.x * 64;
    const int k0 = blockIdx.y * 64;
    const int tid = threadIdx.x;
#pragma unroll
    for (int i = 0; i < 16; ++i) {
        int flat = i * 256 + tid;
        int kr = flat >> 6, nc = flat & 63;
        tile[kr][nc] = W[(size_t)(k0 + kr) * 1024 + n0 + nc];
    }
    __syncthreads();
#pragma unroll
    for (int i = 0; i < 16; ++i) {
        int flat = i * 256 + tid;
        int nr = flat >> 6, kc = flat & 63;
        float v = tile[kc][nr];
        unsigned short h = f2bf(v);
        wh[(size_t)(n0 + nr) * 1024 + k0 + kc] = h;
        wl[(size_t)(n0 + nr) * 1024 + k0 + kc] = f2bf(v - bf2f(h));
    }
}

// ---------------- Q-only fp32 GEMM (bit-identical, grid x=8) -------------
__global__ __launch_bounds__(256) void k_qkv(const float* __restrict__ A,
                                             const float* __restrict__ W,
                                             const float* __restrict__ bias,
                                             const float* __restrict__ tbl,
                                             float* __restrict__ Qb,
                                             float* __restrict__ Kb,
                                             float* __restrict__ Vb)
{
    __shared__ float As[16][128];
    __shared__ float Bs[16][128];
    const int tid = threadIdx.x;
    const int n0 = blockIdx.x * 128;
    const int m0 = blockIdx.y * 128;
    const int tx = tid & 15, ty = tid >> 4;
    float acc[8][8];
#pragma unroll
    for (int i = 0; i < 8; ++i)
#pragma unroll
        for (int j = 0; j < 8; ++j) acc[i][j] = 0.f;

    for (int kt = 0; kt < 1024; kt += 16) {
#pragma unroll
        for (int i = 0; i < 2; ++i) {
            int idx = tid * 2 + i;
            int row = idx >> 2;
            int kq = idx & 3;
            float4 a4 = *(const float4*)(A + (size_t)(m0 + row) * 1024 + kt + kq * 4);
            As[kq * 4 + 0][row] = a4.x;
            As[kq * 4 + 1][row] = a4.y;
            As[kq * 4 + 2][row] = a4.z;
            As[kq * 4 + 3][row] = a4.w;
        }
#pragma unroll
        for (int i = 0; i < 2; ++i) {
            int idx = tid * 2 + i;
            int rr = idx >> 5;
            int c4 = idx & 31;
            *(float4*)(&Bs[rr][c4 * 4]) = *(const float4*)(W + (size_t)(kt + rr) * 3072 + n0 + c4 * 4);
        }
        __syncthreads();
#pragma unroll
        for (int kk = 0; kk < 16; ++kk) {
            float a[8], b[8];
            *(float4*)(a)     = *(const float4*)(&As[kk][ty * 8]);
            *(float4*)(a + 4) = *(const float4*)(&As[kk][ty * 8 + 4]);
            *(float4*)(b)     = *(const float4*)(&Bs[kk][tx * 8]);
            *(float4*)(b + 4) = *(const float4*)(&Bs[kk][tx * 8 + 4]);
#pragma unroll
            for (int i = 0; i < 8; ++i)
#pragma unroll
                for (int j = 0; j < 8; ++j)
                    acc[i][j] = fmaf(a[i], b[j], acc[i][j]);
        }
        __syncthreads();
    }
    const int cbase = n0 + tx * 8;
    const int part = cbase >> 10;
    const int cc = cbase & 1023;
    const int h = cc >> 6;
    const int dbase = cc & 63;
    const int bb = m0 >> 12;
    const int tbase = (m0 & 4095) + ty * 8;
    float bv[8];
#pragma unroll
    for (int j = 0; j < 8; ++j) bv[j] = bias[cbase + j];

    if (part == 2) {
#pragma unroll
        for (int i = 0; i < 8; ++i) {
            int t = tbase + i;
            float* dst = Vb + ((size_t)(bb * 16 + h) * 4096 + t) * 64 + dbase;
            *(float4*)(dst)     = make_float4(acc[i][0] + bv[0], acc[i][1] + bv[1], acc[i][2] + bv[2], acc[i][3] + bv[3]);
            *(float4*)(dst + 4) = make_float4(acc[i][4] + bv[4], acc[i][5] + bv[5], acc[i][6] + bv[6], acc[i][7] + bv[7]);
        }
    } else {
        float* DST = (part == 0) ? Qb : Kb;
#pragma unroll
        for (int i = 0; i < 8; ++i) {
            int t = tbase + i;
            const float4* tb = (const float4*)(tbl + t * 128 + dbase * 2);
            float o[8];
#pragma unroll
            for (int jp = 0; jp < 4; ++jp) {
                float4 cs = tb[jp];
                float ae = acc[i][jp * 2]     + bv[jp * 2];
                float ao = acc[i][jp * 2 + 1] + bv[jp * 2 + 1];
                o[jp * 2]     = ae * cs.x - ao * cs.y;
                o[jp * 2 + 1] = ao * cs.z + ae * cs.w;
            }
            float* dst = DST + ((size_t)(bb * 16 + h) * 4096 + t) * 64 + dbase;
            *(float4*)(dst)     = make_float4(o[0], o[1], o[2], o[3]);
            *(float4*)(dst + 4) = make_float4(o[4], o[5], o[6], o[7]);
        }
    }
}

// ---------------- K,V via split-bf16 MFMA ----------------
__global__ __launch_bounds__(256) void k_kv(const unsigned short* __restrict__ xh,
                                            const unsigned short* __restrict__ xl,
                                            const unsigned short* __restrict__ wh,
                                            const unsigned short* __restrict__ wl,
                                            const float* __restrict__ bias,
                                            const float* __restrict__ tbl,
                                            float* __restrict__ Kb,
                                            float* __restrict__ Vb)
{
    __shared__ unsigned short Ah[128 * 32], Al[128 * 32], Bh[128 * 32], Bl[128 * 32];
    const int tid = threadIdx.x;
    const int lane = tid & 63, wv = tid >> 6;
    const int n0 = blockIdx.x * 128;
    const int m0 = blockIdx.y * 128;
    const int wm = (wv & 1) * 64, wn = (wv >> 1) * 64;
    const int sr = tid >> 2, sc = tid & 3;
    const int fr = lane & 15, fq = lane >> 4;

    floatx4 acc[4][4];
#pragma unroll
    for (int i = 0; i < 4; ++i)
#pragma unroll
        for (int j = 0; j < 4; ++j) acc[i][j] = (floatx4){0.f, 0.f, 0.f, 0.f};

    for (int kt = 0; kt < 1024; kt += 32) {
        __syncthreads();
#pragma unroll
        for (int s = 0; s < 2; ++s) {
            int row = s * 64 + sr;
            size_t ga = (size_t)(m0 + row) * 1024 + kt + sc * 8;
            size_t gb = (size_t)(n0 + row) * 1024 + kt + sc * 8;
            *(short8*)(&Ah[row * 32 + sc * 8]) = *(const short8*)(xh + ga);
            *(short8*)(&Al[row * 32 + sc * 8]) = *(const short8*)(xl + ga);
            *(short8*)(&Bh[row * 32 + sc * 8]) = *(const short8*)(wh + gb);
            *(short8*)(&Bl[row * 32 + sc * 8]) = *(const short8*)(wl + gb);
        }
        __syncthreads();

        bf16x8 afh[4], afl[4], bfh[4], bfl[4];
#pragma unroll
        for (int i = 0; i < 4; ++i) {
            afh[i] = __builtin_bit_cast(bf16x8, *(const short8*)(&Ah[(wm + i * 16 + fr) * 32 + fq * 8]));
            afl[i] = __builtin_bit_cast(bf16x8, *(const short8*)(&Al[(wm + i * 16 + fr) * 32 + fq * 8]));
            bfh[i] = __builtin_bit_cast(bf16x8, *(const short8*)(&Bh[(wn + i * 16 + fr) * 32 + fq * 8]));
            bfl[i] = __builtin_bit_cast(bf16x8, *(const short8*)(&Bl[(wn + i * 16 + fr) * 32 + fq * 8]));
        }
#pragma unroll
        for (int i = 0; i < 4; ++i)
#pragma unroll
            for (int j = 0; j < 4; ++j) {
                acc[i][j] = __builtin_amdgcn_mfma_f32_16x16x32_bf16(afh[i], bfh[j], acc[i][j], 0, 0, 0);
                acc[i][j] = __builtin_amdgcn_mfma_f32_16x16x32_bf16(afh[i], bfl[j], acc[i][j], 0, 0, 0);
                acc[i][j] = __builtin_amdgcn_mfma_f32_16x16x32_bf16(afl[i], bfh[j], acc[i][j], 0, 0, 0);
            }
    }

#pragma unroll
    for (int j = 0; j < 4; ++j) {
        int nn = n0 + wn + j * 16 + fr;
        float bv = bias[1024 + nn];
#pragma unroll
        for (int i = 0; i < 4; ++i) {
#pragma unroll
            for (int r = 0; r < 4; ++r) {
                int mm = m0 + wm + i * 16 + fq * 4 + r;
                int t = mm & 4095, bb = mm >> 12;
                float y = acc[i][j][r] + bv;
                if (nn < 1024) {
                    int h = nn >> 6, d = nn & 63;
                    float part = __shfl_xor(y, 1);
                    float c = tbl[t * 128 + d * 2];
                    float s = tbl[t * 128 + d * 2 + 1];
                    float o = (d & 1) ? fmaf(part, s, y * c) : fmaf(-part, s, y * c);
                    Kb[((size_t)(bb * 16 + h) * 4096 + t) * 64 + d] = o;
                } else {
                    int nv = nn - 1024;
                    int h = nv >> 6, d = nv & 63;
                    Vb[((size_t)(bb * 16 + h) * 4096 + t) * 64 + d] = y;
                }
            }
        }
    }
}

// ---------------- bucket argmax ----------------
__global__ __launch_bounds__(64) void k_bucket(const float* __restrict__ Q,
                                               const float* __restrict__ R,
                                               int* __restrict__ bidx)
{
    __shared__ float Qs[64][65];
    __shared__ float Rs[64][32];
    const int tid = threadIdx.x;
    const int g0 = blockIdx.x * 64;
    const int bh = g0 >> 12;
    const int t0 = g0 & 4095;
#pragma unroll
    for (int m = 0; m < 32; ++m) Rs[tid][m] = R[tid * 64 + m];
    const float* qbase = Q + ((size_t)bh * Tz + t0) * 64;
    for (int r = 0; r < 64; ++r) Qs[r][tid] = qbase[(size_t)r * 64 + tid];
    __syncthreads();

    float s[32];
#pragma unroll
    for (int m = 0; m < 32; ++m) s[m] = 0.f;
    for (int d = 0; d < 64; ++d) {
        float qd = Qs[tid][d];
#pragma unroll
        for (int m4 = 0; m4 < 8; ++m4) {
            float4 r4 = *(const float4*)(&Rs[d][m4 * 4]);
            s[m4 * 4 + 0] = fmaf(qd, r4.x, s[m4 * 4 + 0]);
            s[m4 * 4 + 1] = fmaf(qd, r4.y, s[m4 * 4 + 1]);
            s[m4 * 4 + 2] = fmaf(qd, r4.z, s[m4 * 4 + 2]);
            s[m4 * 4 + 3] = fmaf(qd, r4.w, s[m4 * 4 + 3]);
        }
    }
    float best = s[0];
    int bi = 0;
#pragma unroll
    for (int m = 1; m < 64; ++m) {
        float v = (m < 32) ? s[m] : -s[m - 32];
        if (v > best) { best = v; bi = m; }
    }
    bidx[g0 + tid] = bi;
}

// ---------------- stable counting sort ----------------
__global__ __launch_bounds__(64) void k_sort(const int* __restrict__ bidx,
                                             int* __restrict__ sidx)
{
    __shared__ int lb[4096];
    __shared__ int ls[4096];
    const int tid = threadIdx.x;
    const int bh = blockIdx.x;
    const int* brow = bidx + (size_t)bh * 4096;
    for (int i = tid; i < 4096; i += 64) lb[i] = brow[i];
    __syncthreads();
    int cnt = 0;
    for (int i = 0; i < 4096; ++i) cnt += (lb[i] == tid);
    int run = cnt;
#pragma unroll
    for (int off = 1; off < 64; off <<= 1) {
        int n = __shfl_up(run, off, 64);
        if (tid >= off) run += n;
    }
    int pos = run - cnt;
    for (int i = 0; i < 4096; ++i) {
        if (lb[i] == tid) { ls[pos] = i; ++pos; }
    }
    __syncthreads();
    int* srow = sidx + (size_t)bh * 4096;
    for (int i = tid; i < 4096; i += 64) srow[i] = ls[i];
}

// ---------------- chunked attention via MFMA (m120 pattern) --------------
// LDS (ushort): Kh[128][72]@0, Kl[128][72]@9216 ; P[128][144] overlays @0 after S
//               Vt[64][144]@18432  (dim-major)   total 27648 us = 55296 B
__global__ __launch_bounds__(256) void k_attn(const float* __restrict__ Q,
                                              const float* __restrict__ Kg,
                                              const float* __restrict__ Vg,
                                              const int* __restrict__ sidx,
                                              unsigned short* __restrict__ AOh,
                                              unsigned short* __restrict__ AOl)
{
    __shared__ unsigned short smem[27648];
    unsigned short* KhS = smem;
    unsigned short* KlS = smem + 9216;
    unsigned short* PbS = smem;
    unsigned short* VtS = smem + 18432;

    const int bh = blockIdx.y;
    const int ch = blockIdx.x;
    const int tid = threadIdx.x;
    const int lane = tid & 63;
    const int w = tid >> 6;
    const int c = lane & 15;   // frag row/col
    const int q = lane >> 4;   // quad
    const int* srow = sidx + (size_t)bh * Tz + ch * 128;

    // ---- stage K (bf16 hi/lo) and V^T (bf16) ----
    {
        const int r = tid >> 1;
        const int d0 = (tid & 1) * 32;
        int orig = srow[r];
        const float* kp = Kg + ((size_t)bh * Tz + orig) * 64 + d0;
        const float* vp = Vg + ((size_t)bh * Tz + orig) * 64 + d0;
#pragma unroll
        for (int j4 = 0; j4 < 8; ++j4) {
            float4 k4 = *(const float4*)(kp + j4 * 4);
            ushort4 h4, l4;
            h4.x = f2bf(k4.x); l4.x = f2bf(k4.x - bf2f(h4.x));
            h4.y = f2bf(k4.y); l4.y = f2bf(k4.y - bf2f(h4.y));
            h4.z = f2bf(k4.z); l4.z = f2bf(k4.z - bf2f(h4.z));
            h4.w = f2bf(k4.w); l4.w = f2bf(k4.w - bf2f(h4.w));
            *(ushort4*)(&KhS[r * 72 + d0 + j4 * 4]) = h4;
            *(ushort4*)(&KlS[r * 72 + d0 + j4 * 4]) = l4;
            float4 v4 = *(const float4*)(vp + j4 * 4);
            int db = d0 + j4 * 4;
            VtS[(db + 0) * 144 + r] = f2bf(v4.x);
            VtS[(db + 1) * 144 + r] = f2bf(v4.y);
            VtS[(db + 2) * 144 + r] = f2bf(v4.z);
            VtS[(db + 3) * 144 + r] = f2bf(v4.w);
        }
    }

    // ---- Q fragments from global into registers (bf16 hi/lo) ----
    bf16x8 qh[2][2], ql[2][2];
#pragma unroll
    for (int i = 0; i < 2; ++i) {
        int row = w * 32 + i * 16 + c;
        int orig = srow[row];
        const float* qp = Q + ((size_t)bh * Tz + orig) * 64 + q * 8;
#pragma unroll
        for (int kc = 0; kc < 2; ++kc) {
            float4 fa = *(const float4*)(qp + kc * 32);
            float4 fb = *(const float4*)(qp + kc * 32 + 4);
            float f[8] = {fa.x, fa.y, fa.z, fa.w, fb.x, fb.y, fb.z, fb.w};
            short8 hh, ll;
#pragma unroll
            for (int e = 0; e < 8; ++e) {
                unsigned short h = f2bf(f[e]);
                hh[e] = (short)h;
                ll[e] = (short)f2bf(f[e] - bf2f(h));
            }
            qh[i][kc] = __builtin_bit_cast(bf16x8, hh);
            ql[i][kc] = __builtin_bit_cast(bf16x8, ll);
        }
    }
    __syncthreads();

    // ---- S = Q K^T (3-term split) ----
    floatx4 accs[2][8];
#pragma unroll
    for (int i = 0; i < 2; ++i)
#pragma unroll
        for (int j = 0; j < 8; ++j) accs[i][j] = (floatx4){0.f, 0.f, 0.f, 0.f};

#pragma unroll
    for (int j = 0; j < 8; ++j) {
        int n = j * 16 + c;
        bf16x8 kbh[2], kbl[2];
#pragma unroll
        for (int kc = 0; kc < 2; ++kc) {
            kbh[kc] = __builtin_bit_cast(bf16x8, *(const short8*)(&KhS[n * 72 + kc * 32 + q * 8]));
            kbl[kc] = __builtin_bit_cast(bf16x8, *(const short8*)(&KlS[n * 72 + kc * 32 + q * 8]));
        }
#pragma unroll
        for (int i = 0; i < 2; ++i)
#pragma unroll
            for (int kc = 0; kc < 2; ++kc) {
                accs[i][j] = __builtin_amdgcn_mfma_f32_16x16x32_bf16(qh[i][kc], kbh[kc], accs[i][j], 0, 0, 0);
                accs[i][j] = __builtin_amdgcn_mfma_f32_16x16x32_bf16(qh[i][kc], kbl[kc], accs[i][j], 0, 0, 0);
                accs[i][j] = __builtin_amdgcn_mfma_f32_16x16x32_bf16(ql[i][kc], kbh[kc], accs[i][j], 0, 0, 0);
            }
    }

    // ---- softmax over rows (row = w*32 + i*16 + q*4 + r) ----
    float linv[2][4];
#pragma unroll
    for (int i = 0; i < 2; ++i) {
#pragma unroll
        for (int r = 0; r < 4; ++r) {
            float mm = -1e30f;
#pragma unroll
            for (int j = 0; j < 8; ++j) {
                float v = accs[i][j][r] * 0.125f;
                accs[i][j][r] = v;
                mm = fmaxf(mm, v);
            }
#pragma unroll
            for (int off = 1; off < 16; off <<= 1) mm = fmaxf(mm, __shfl_xor(mm, off));
            float ss = 0.f;
#pragma unroll
            for (int j = 0; j < 8; ++j) {
                float p = expf(accs[i][j][r] - mm);
                accs[i][j][r] = p;
                ss += p;
            }
#pragma unroll
            for (int off = 1; off < 16; off <<= 1) ss += __shfl_xor(ss, off);
            linv[i][r] = 1.0f / ss;
        }
    }
    __syncthreads();   // all K reads done; safe to overlay P

    // ---- write P (bf16) rows [w*32, w*32+32) ----
#pragma unroll
    for (int i = 0; i < 2; ++i)
#pragma unroll
        for (int j = 0; j < 8; ++j)
#pragma unroll
            for (int r = 0; r < 4; ++r)
                PbS[(w * 32 + i * 16 + q * 4 + r) * 144 + j * 16 + c] = f2bf(accs[i][j][r]);
    // own-rows only: no barrier needed (same-wave write->read ordering via lgkmcnt)

    // ---- O = P V ----
    floatx4 acco[2][4];
#pragma unroll
    for (int i = 0; i < 2; ++i)
#pragma unroll
        for (int jf = 0; jf < 4; ++jf) acco[i][jf] = (floatx4){0.f, 0.f, 0.f, 0.f};

#pragma unroll
    for (int kc = 0; kc < 4; ++kc) {
        bf16x8 pa[2];
#pragma unroll
        for (int i = 0; i < 2; ++i)
            pa[i] = __builtin_bit_cast(bf16x8, *(const short8*)(&PbS[(w * 32 + i * 16 + c) * 144 + kc * 32 + q * 8]));
#pragma unroll
        for (int jf = 0; jf < 4; ++jf) {
            bf16x8 vb = __builtin_bit_cast(bf16x8, *(const short8*)(&VtS[(jf * 16 + c) * 144 + kc * 32 + q * 8]));
            acco[0][jf] = __builtin_amdgcn_mfma_f32_16x16x32_bf16(pa[0], vb, acco[0][jf], 0, 0, 0);
            acco[1][jf] = __builtin_amdgcn_mfma_f32_16x16x32_bf16(pa[1], vb, acco[1][jf], 0, 0, 0);
        }
    }

    // ---- epilogue: normalize, split bf16, scatter-unsort ----
    const int bb = bh >> 4, hh = bh & 15;
#pragma unroll
    for (int i = 0; i < 2; ++i) {
#pragma unroll
        for (int r = 0; r < 4; ++r) {
            int row = w * 32 + i * 16 + q * 4 + r;
            int orig = srow[row];
            float inv = linv[i][r];
            size_t base = ((size_t)bb * 4096 + orig) * 1024 + hh * 64 + c;
#pragma unroll
            for (int jf = 0; jf < 4; ++jf) {
                float val = acco[i][jf][r] * inv;
                unsigned short h = f2bf(val);
                unsigned short l = f2bf(val - bf2f(h));
                AOh[base + jf * 16] = h;
                AOl[base + jf * 16] = l;
            }
        }
    }
}

// ---------------- output projection via split-bf16 MFMA ----------------
__global__ __launch_bounds__(256) void k_proj(const unsigned short* __restrict__ ah,
                                              const unsigned short* __restrict__ al,
                                              const unsigned short* __restrict__ wh,
                                              const unsigned short* __restrict__ wl,
                                              const float* __restrict__ bias,
                                              float* __restrict__ Cout)
{
    __shared__ unsigned short Ah[128 * 32], Al[128 * 32], Bh[128 * 32], Bl[128 * 32];
    const int tid = threadIdx.x;
    const int lane = tid & 63, wv = tid >> 6;
    const int n0 = blockIdx.x * 128;
    const int m0 = blockIdx.y * 128;
    const int wm = (wv & 1) * 64, wn = (wv >> 1) * 64;
    const int sr = tid >> 2, sc = tid & 3;
    const int fr = lane & 15, fq = lane >> 4;

    floatx4 acc[4][4];
#pragma unroll
    for (int i = 0; i < 4; ++i)
#pragma unroll
        for (int j = 0; j < 4; ++j) acc[i][j] = (floatx4){0.f, 0.f, 0.f, 0.f};

    for (int kt = 0; kt < 1024; kt += 32) {
        __syncthreads();
#pragma unroll
        for (int s = 0; s < 2; ++s) {
            int row = s * 64 + sr;
            size_t ga = (size_t)(m0 + row) * 1024 + kt + sc * 8;
            size_t gb = (size_t)(n0 + row) * 1024 + kt + sc * 8;
            *(short8*)(&Ah[row * 32 + sc * 8]) = *(const short8*)(ah + ga);
            *(short8*)(&Al[row * 32 + sc * 8]) = *(const short8*)(al + ga);
            *(short8*)(&Bh[row * 32 + sc * 8]) = *(const short8*)(wh + gb);
            *(short8*)(&Bl[row * 32 + sc * 8]) = *(const short8*)(wl + gb);
        }
        __syncthreads();

        bf16x8 afh[4], afl[4], bfh[4], bfl[4];
#pragma unroll
        for (int i = 0; i < 4; ++i) {
            afh[i] = __builtin_bit_cast(bf16x8, *(const short8*)(&Ah[(wm + i * 16 + fr) * 32 + fq * 8]));
            afl[i] = __builtin_bit_cast(bf16x8, *(const short8*)(&Al[(wm + i * 16 + fr) * 32 + fq * 8]));
            bfh[i] = __builtin_bit_cast(bf16x8, *(const short8*)(&Bh[(wn + i * 16 + fr) * 32 + fq * 8]));
            bfl[i] = __builtin_bit_cast(bf16x8, *(const short8*)(&Bl[(wn + i * 16 + fr) * 32 + fq * 8]));
        }
#pragma unroll
        for (int i = 0; i < 4; ++i)
#pragma unroll
            for (int j = 0; j < 4; ++j) {
                acc[i][j] = __builtin_amdgcn_mfma_f32_16x16x32_bf16(afh[i], bfh[j], acc[i][j], 0, 0, 0);
                acc[i][j] = __builtin_amdgcn_mfma_f32_16x16x32_bf16(afh[i], bfl[j], acc[i][j], 0, 0, 0);
                acc[i][j] = __builtin_amdgcn_mfma_f32_16x16x32_bf16(afl[i], bfh[j], acc[i][j], 0, 0, 0);
            }
    }

#pragma unroll
    for (int j = 0; j < 4; ++j) {
        int nn = n0 + wn + j * 16 + fr;
        float bv = bias[nn];
#pragma unroll
        for (int i = 0; i < 4; ++i) {
#pragma unroll
            for (int r = 0; r < 4; ++r) {
                int mm = m0 + wm + i * 16 + fq * 4 + r;
                Cout[(size_t)mm * 1024 + nn] = acc[i][j][r] + bv;
            }
        }
    }
}

extern "C" void kernel_launch(void* const* d_in, const int* in_sizes, int n_in,
                              void* d_out, int out_size, void* d_ws, size_t ws_size,
                              hipStream_t stream)
{
    const float* x      = (const float*)d_in[0];
    const float* W_attn = (const float*)d_in[1];
    const float* b_attn = (const float*)d_in[2];
    const float* W_proj = (const float*)d_in[3];
    const float* b_proj = (const float*)d_in[4];
    const float* R      = (const float*)d_in[5];
    float* out = (float*)d_out;

    char* ws = (char*)d_ws;
    const size_t MB = 1024 * 1024;
    float*          tbl  = (float*)(ws);                    // 2 MB
    float*          Qb   = (float*)(ws + 2 * MB);           // 64 MB
    float*          Kb   = (float*)(ws + 66 * MB);          // 64 MB
    unsigned short* xh   = (unsigned short*)(ws + 130 * MB);// 32 MB
    unsigned short* xl   = (unsigned short*)(ws + 162 * MB);// 32 MB
    unsigned short* AOh  = (unsigned short*)(ws + 130 * MB);// 32 MB (alias xh)
    unsigned short* AOl  = (unsigned short*)(ws + 162 * MB);// 32 MB (alias xl)
    int*            bidx = (int*)(ws + 194 * MB);           // 1 MB
    int*            sidx = (int*)(ws + 195 * MB);           // 1 MB
    unsigned short* wth  = (unsigned short*)(ws + 196 * MB);// 4 MB
    unsigned short* wtl  = (unsigned short*)(ws + 200 * MB);// 4 MB
    unsigned short* wph  = (unsigned short*)(ws + 196 * MB);// 2 MB (alias wth, after k_kv)
    unsigned short* wpl  = (unsigned short*)(ws + 200 * MB);// 2 MB (alias wtl, after k_kv)
    float*          Vb   = (float*)d_out;                   // scratch until k_proj

    k_trig  <<<dim3(16),       dim3(256), 0, stream>>>(tbl);
    k_cvtA  <<<dim3(16384),    dim3(256), 0, stream>>>(x, xh, xl);
    k_cvtB  <<<dim3(32, 16),   dim3(256), 0, stream>>>(W_attn, wth, wtl);
    k_qkv   <<<dim3(8, 128),   dim3(256), 0, stream>>>(x, W_attn, b_attn, tbl, Qb, Kb, Vb);
    k_kv    <<<dim3(16, 128),  dim3(256), 0, stream>>>(xh, xl, wth, wtl, b_attn, tbl, Kb, Vb);
    k_cvtP  <<<dim3(16, 16),   dim3(256), 0, stream>>>(W_proj, wph, wpl);
    k_bucket<<<dim3(4096),     dim3(64),  0, stream>>>(Qb, R, bidx);
    k_sort  <<<dim3(64),       dim3(64),  0, stream>>>(bidx, sidx);
    k_attn  <<<dim3(32, 64),   dim3(256), 0, stream>>>(Qb, Kb, Vb, sidx, AOh, AOl);
    k_proj  <<<dim3(8, 128),   dim3(256), 0, stream>>>(AOh, AOl, wph, wpl, b_proj, out);
}